// Round 13
// baseline (26871.539 us; speedup 1.0000x reference)
//
#include <hip/hip_runtime.h>
#include <hip/hip_bf16.h>
#include <math.h>

#define B_   64
#define T_   256
#define DIN_ 512
#define H_   512
#define D_   1024
#define O_   1536
#define TB_  (T_*B_)
#define EPSf 1e-5f
#define NWG  96          // persistent WGs; WG w owns y-cols [16w,16w+16)
#define NSLOT (T_ + 6)   // wavefront slots: t = s - 2l

typedef short  bf16x8 __attribute__((ext_vector_type(8)));
typedef float  f32x4  __attribute__((ext_vector_type(4)));
typedef ushort u16x4  __attribute__((ext_vector_type(4)));

#define SPLIT1(f, Hm, Lm) { __hip_bfloat16 _h = __float2bfloat16(f); (Hm) = *(ushort*)&_h; \
    __hip_bfloat16 _l = __float2bfloat16((f) - __bfloat162float(_h)); (Lm) = *(ushort*)&_l; }

__device__ inline float bfu2f(ushort u) {
    __hip_bfloat16 b = *(__hip_bfloat16*)&u;
    return __bfloat162float(b);
}
__device__ inline void st_f32_coh(float* p, float v) {
    __hip_atomic_store(p, v, __ATOMIC_RELAXED, __HIP_MEMORY_SCOPE_AGENT);
}
__device__ inline void st_u16_coh(ushort* p, ushort v) {
    __hip_atomic_store(p, v, __ATOMIC_RELAXED, __HIP_MEMORY_SCOPE_AGENT);
}
__device__ inline void st_f32x2_coh(float* p, float a, float b) {
    union { float f[2]; unsigned long long u; } pk;
    pk.f[0] = a; pk.f[1] = b;
    __hip_atomic_store((unsigned long long*)p, pk.u, __ATOMIC_RELAXED,
                       __HIP_MEMORY_SCOPE_AGENT);
}

// ---------------- mask codes: mcode[t*B+b] = mt | (mn<<1) ----------------
__global__ __launch_bounds__(256) void k_mask(const int* __restrict__ mask,
                                              int* __restrict__ mcode) {
    int g = blockIdx.x * 256 + threadIdx.x;
    int t = g >> 6, b = g & 63;
    int mt = mask[b * T_ + t] != 0;
    int mn = (t + 1 < T_) ? (mask[b * T_ + t + 1] != 0) : 0;
    mcode[g] = mt | (mn << 1);
}

// ---- x split: Xb0[t*64+b][k] = split(k<512 ? x[b][t][k] : 0) ----
__global__ __launch_bounds__(256) void k_prepx(const float* __restrict__ x,
                                               ushort* __restrict__ Xh,
                                               ushort* __restrict__ Xl) {
    int g  = blockIdx.x * 256 + threadIdx.x;
    int i4 = g * 4;
    int row = i4 >> 10;
    int k   = i4 & 1023;
    int t = row >> 6, b = row & 63;
    float4 v = make_float4(0.f, 0.f, 0.f, 0.f);
    if (k < 512) v = *(const float4*)&x[((size_t)b * T_ + t) * 512 + k];
    u16x4 h, l;
    SPLIT1(v.x, h[0], l[0]); SPLIT1(v.y, h[1], l[1]);
    SPLIT1(v.z, h[2], l[2]); SPLIT1(v.w, h[3], l[3]);
    *(u16x4*)&Xh[i4] = h;
    *(u16x4*)&Xl[i4] = l;
}

// ---- transpose + split-bf16: Mt_hi[o][k]+Mt_lo[o][k] ≈ M[k][o]  (M is [D_][O_]) ----
__global__ __launch_bounds__(256) void k_prep(const float* __restrict__ M,
                                              ushort* __restrict__ Mt_hi,
                                              ushort* __restrict__ Mt_lo) {
    __shared__ float ls[64][65];
    int k0 = blockIdx.y * 64;
    int o0 = blockIdx.x * 64;
    int tid = threadIdx.x;
    int r = tid >> 2, cq = tid & 3;
#pragma unroll
    for (int j = 0; j < 4; ++j) {
        float4 v = *(const float4*)&M[(size_t)(k0 + r) * O_ + o0 + cq * 16 + j * 4];
        ls[r][cq * 16 + j * 4 + 0] = v.x;
        ls[r][cq * 16 + j * 4 + 1] = v.y;
        ls[r][cq * 16 + j * 4 + 2] = v.z;
        ls[r][cq * 16 + j * 4 + 3] = v.w;
    }
    __syncthreads();
    int ol = tid >> 2, kq = tid & 3;
    ushort th[16], tl[16];
#pragma unroll
    for (int j = 0; j < 16; ++j) {
        float v = ls[kq * 16 + j][ol];
        SPLIT1(v, th[j], tl[j]);
    }
    size_t base = (size_t)(o0 + ol) * D_ + k0 + kq * 16;
    *(int4*)&Mt_hi[base]     = *(int4*)&th[0];
    *(int4*)&Mt_hi[base + 8] = *(int4*)&th[8];
    *(int4*)&Mt_lo[base]     = *(int4*)&tl[0];
    *(int4*)&Mt_lo[base + 8] = *(int4*)&tl[8];
}

// ------ barrier: sc1-store protocol (verified round 8) ------
__device__ inline void gbar(unsigned* __restrict__ fl, int w, unsigned bar) {
    __syncthreads();
    asm volatile("s_waitcnt vmcnt(0)" ::: "memory");
    if (threadIdx.x == 0)
        __hip_atomic_store(&fl[w], bar, __ATOMIC_RELAXED, __HIP_MEMORY_SCOPE_AGENT);
    if (threadIdx.x < NWG) {
        while (__hip_atomic_load(&fl[threadIdx.x], __ATOMIC_RELAXED,
                                 __HIP_MEMORY_SCOPE_AGENT) < bar)
            __builtin_amdgcn_s_sleep(2);
    }
    __syncthreads();
    __builtin_amdgcn_fence(__ATOMIC_ACQUIRE, "agent");
}

// ============ 4-layer wavefront pipeline: wave = (layer, row-half) ============
// 96 WGs x 512 thr. WG w owns cols [16w,16w+16). wave v: layer l=v&3,
// rows [(v>>2)*32, +32) as two 16-row MFMA tiles. Layers run CONCURRENTLY.
// slot s: layer l does step t=s-2l. 2 device barriers/slot; stats via LDS.
__global__ __launch_bounds__(512, 1) void k_pipe(
        const float* __restrict__ x,
        const ushort* __restrict__ Xbh, const ushort* __restrict__ Xbl,
        ushort* __restrict__ Xrh, ushort* __restrict__ Xrl,
        ushort* __restrict__ Hbh, ushort* __restrict__ Hbl,
        float* __restrict__ Y1, float* __restrict__ Y2,
        float* __restrict__ pstats, float* __restrict__ FKr,
        unsigned* __restrict__ flags,
        const ushort* __restrict__ Uth, const ushort* __restrict__ Utl,
        const ushort* __restrict__ Wth, const ushort* __restrict__ Wtl,
        const float* __restrict__ gam, const float* __restrict__ bet,
        const float* __restrict__ bias,
        const int* __restrict__ mcode, float* __restrict__ out) {
    __shared__ __hip_bfloat16 lds[4 * 16 * 1024];   // [U_hi|U_lo|W_hi|W_lo] 32KB each
    __shared__ float4 ldsfin[256];                  // finals[(l,b)] = m1,i1,m2,i2
    const int w = blockIdx.x;
    const int tid = threadIdx.x;
    const int lane = tid & 63;
    const int v = tid >> 6;            // wave 0..7
    const int l = v & 3;               // this wave's layer
    const int rh = v >> 2;             // row half 0..1
    const int lr = lane & 15;
    const int lg = lane >> 4;
    const int c0 = w * 16;

    // stage U/W tiles (cols c0..c0+16) into LDS, XOR-swizzled (512 threads)
    {
        int cl = tid >> 5, kc5 = tid & 31;
        const ushort* s0 = Uth + (size_t)(c0 + cl) * D_ + kc5 * 32;
        const ushort* s1 = Utl + (size_t)(c0 + cl) * D_ + kc5 * 32;
        const ushort* s2 = Wth + (size_t)(c0 + cl) * D_ + kc5 * 32;
        const ushort* s3 = Wtl + (size_t)(c0 + cl) * D_ + kc5 * 32;
        char* base = (char*)lds;
#pragma unroll
        for (int j = 0; j < 4; ++j) {
            int k = kc5 * 32 + j * 8;
            int off = (cl * 2048 + k * 2) ^ ((cl & 7) << 4);
            *(int4*)(base + off)         = *(const int4*)(s0 + j * 8);
            *(int4*)(base + 32768 + off) = *(const int4*)(s1 + j * 8);
            *(int4*)(base + 65536 + off) = *(const int4*)(s2 + j * 8);
            *(int4*)(base + 98304 + off) = *(const int4*)(s3 + j * 8);
        }
    }
    __syncthreads();

    const int d = c0 + lr;
    const bool gate_wg = (w < 64);
    const bool tanh_wg = (w >= 32 && w < 64);
    float g0d = 0.f, g1d = 0.f, cd = 0.f, g0e = 0.f, g1e = 0.f, ce = 0.f;
    if (gate_wg) {
        g0d = gam[d]; g1d = gam[O_ + d];
        cd  = bet[d] + bet[O_ + d] + bias[d];
    }
    if (tanh_wg) {
        int e = d + 512;
        g0e = gam[e]; g1e = gam[O_ + e];
        ce  = bet[e] + bet[O_ + e] + bias[e];
    }

    // this wave's per-row recurrent state (8 rows/lane: rt in {0,1}, j in {0..3})
    float h1r[2][4] = {}, fk1r[2][4] = {};
    f32x4 acc1[2], acc2[2];

    unsigned bar = 0;
    for (int s = 0; s < NSLOT; ++s) {
        const int t = s - 2 * l;
        const bool act = (t >= 0) && (t < T_);
        // ---------------- phase A: this wave's layer matvec ----------------
        if (act) {
#pragma unroll
            for (int rt = 0; rt < 2; ++rt) {
                const int b0 = rh * 32 + rt * 16;
                const ushort *xsh, *xsl;
                if (l == 0) {
                    xsh = Xbh + ((size_t)t * B_ + b0 + lr) * D_;
                    xsl = Xbl + ((size_t)t * B_ + b0 + lr) * D_;
                } else {
                    size_t rb = (((size_t)l * 3 + (t % 3)) * B_ + b0 + lr) * D_;
                    xsh = Xrh + rb;
                    xsl = Xrl + rb;
                }
                const ushort* hsh = Hbh + ((size_t)l * B_ + b0 + lr) * D_;
                const ushort* hsl = Hbl + ((size_t)l * B_ + b0 + lr) * D_;
                const char* lb = (const char*)lds;
                f32x4 a10 = {0,0,0,0}, a11 = {0,0,0,0}, a12 = {0,0,0,0};
                f32x4 a20 = {0,0,0,0}, a21 = {0,0,0,0}, a22 = {0,0,0,0};
#pragma unroll 4
                for (int kc = 0; kc < 32; ++kc) {
                    int k = kc * 32 + lg * 8;
                    int off = (lr * 2048 + k * 2) ^ ((lr & 7) << 4);
                    bf16x8 xah = *(const bf16x8*)(xsh + k);
                    bf16x8 xal = *(const bf16x8*)(xsl + k);
                    bf16x8 hah = *(const bf16x8*)(hsh + k);
                    bf16x8 hal = *(const bf16x8*)(hsl + k);
                    bf16x8 ubh = *(const bf16x8*)(lb + off);
                    bf16x8 ubl = *(const bf16x8*)(lb + 32768 + off);
                    bf16x8 wbh = *(const bf16x8*)(lb + 65536 + off);
                    bf16x8 wbl = *(const bf16x8*)(lb + 98304 + off);
                    a10 = __builtin_amdgcn_mfma_f32_16x16x32_bf16(xah, wbh, a10, 0, 0, 0);
                    a11 = __builtin_amdgcn_mfma_f32_16x16x32_bf16(xah, wbl, a11, 0, 0, 0);
                    a12 = __builtin_amdgcn_mfma_f32_16x16x32_bf16(xal, wbh, a12, 0, 0, 0);
                    a20 = __builtin_amdgcn_mfma_f32_16x16x32_bf16(hah, ubh, a20, 0, 0, 0);
                    a21 = __builtin_amdgcn_mfma_f32_16x16x32_bf16(hah, ubl, a21, 0, 0, 0);
                    a22 = __builtin_amdgcn_mfma_f32_16x16x32_bf16(hal, ubh, a22, 0, 0, 0);
                }
                acc1[rt] = a10 + a11 + a12;
                acc2[rt] = a20 + a21 + a22;
                // per-row partial stats over this WG's 16 cols -> pstats
#pragma unroll
                for (int j = 0; j < 4; ++j) {
                    float s1 = acc1[rt][j], q1 = s1 * s1;
                    float s2 = acc2[rt][j], q2 = s2 * s2;
#pragma unroll
                    for (int m = 1; m < 16; m <<= 1) {
                        s1 += __shfl_xor(s1, m); q1 += __shfl_xor(q1, m);
                        s2 += __shfl_xor(s2, m); q2 += __shfl_xor(q2, m);
                    }
                    if (lr == 0) {
                        float* sp = &pstats[(((size_t)l * 64 + b0 + lg * 4 + j) * NWG + w) * 4];
                        st_f32x2_coh(sp, s1, q1);
                        st_f32x2_coh(sp + 2, s2, q2);
                    }
                }
                // tanh-partner col export (w>=64 only)
                if (w >= 64) {
                    int ce2 = c0 + lr - 1024;
#pragma unroll
                    for (int j = 0; j < 4; ++j) {
                        int b = b0 + lg * 4 + j;
                        st_f32_coh(&Y1[((size_t)l * B_ + b) * 512 + ce2], acc1[rt][j]);
                        st_f32_coh(&Y2[((size_t)l * B_ + b) * 512 + ce2], acc2[rt][j]);
                    }
                }
            }
        }
        gbar(flags, w, ++bar);

        // ------- phase C: stats reduce (LDS) + gating, all layers concurrent -------
        if (gate_wg && act) {
            int row = rh * 32 + (lane >> 1);
            int q = lane & 1;
            const float* pp = &pstats[(((size_t)l * 64 + row) * NWG + q * 48) * 4];
            float s1 = 0.f, q1 = 0.f, s2 = 0.f, q2 = 0.f;
#pragma unroll 8
            for (int i = 0; i < 48; ++i) {
                float4 vv = *(const float4*)(pp + i * 4);
                s1 += vv.x; q1 += vv.y; s2 += vv.z; q2 += vv.w;
            }
            s1 += __shfl_xor(s1, 1); q1 += __shfl_xor(q1, 1);
            s2 += __shfl_xor(s2, 1); q2 += __shfl_xor(q2, 1);
            if (q == 0) {
                float m1 = s1 * (1.f / O_);
                float v1 = q1 * (1.f / O_) - m1 * m1;
                float i1 = 1.f / (sqrtf(v1 + EPSf) + EPSf);
                float m2 = s2 * (1.f / O_);
                float v2 = q2 * (1.f / O_) - m2 * m2;
                float i2 = 1.f / (sqrtf(v2 + EPSf) + EPSf);
                ldsfin[l * 64 + row] = make_float4(m1, i1, m2, i2);
            }
        }
        __syncthreads();
        if (gate_wg && act) {
#pragma unroll
            for (int rt = 0; rt < 2; ++rt) {
                const int b0 = rh * 32 + rt * 16;
                int4 mc4 = *(const int4*)&mcode[t * B_ + b0 + lg * 4];
                int mcarr[4] = {mc4.x, mc4.y, mc4.z, mc4.w};
#pragma unroll
                for (int j = 0; j < 4; ++j) {
                    int b = b0 + lg * 4 + j;
                    float4 fin = ldsfin[l * 64 + b];
                    float y1 = acc1[rt][j], y2 = acc2[rt][j];
                    float td = g0d * (y1 - fin.x) * fin.y + g1d * (y2 - fin.z) * fin.w + cd;
                    float fkc = fminf(fmaxf(0.2f * td + 0.5f, 0.f), 1.f);
                    float hpad = 0.f;
                    if (tanh_wg) {
                        float y1e = Y1[((size_t)l * B_ + b) * 512 + (d - 512)];
                        float y2e = Y2[((size_t)l * B_ + b) * 512 + (d - 512)];
                        float te = g0e * (y1e - fin.x) * fin.y + g1e * (y2e - fin.z) * fin.w + ce;
                        hpad = tanhf(te);
                    }
                    float xt;
                    if (l == 0) {
                        xt = (d < 512) ? x[((size_t)b * T_ + t) * 512 + d] : 0.f;
                    } else {
                        size_t rb = (((size_t)l * 3 + (t % 3)) * B_ + b) * D_ + d;
                        xt = bfu2f(Xrh[rb]) + bfu2f(Xrl[rb]);
                    }
                    float fkp = 0.f;
                    if (l > 0 && t + 1 < T_)
                        fkp = FKr[(((size_t)(l - 1) * 2 + ((t + 1) & 1)) * B_ + b) * D_ + d];
                    float hc = (1.f - fkc) * xt + fkc * hpad;
                    float h  = fkp * h1r[rt][j] + (1.f - fkp) * hc;
                    float fk = fkp + (1.f - fkp) * fkc;
                    int mt = mcarr[j] & 1, mn = (mcarr[j] >> 1) & 1;
                    if (mt && !mn) fk = 0.f;
                    float oh  = mt ? h  : h1r[rt][j];
                    float ofk = mt ? fk : fk1r[rt][j];
                    h1r[rt][j] = oh; fk1r[rt][j] = ofk;
                    ushort hi, lo;
                    SPLIT1(oh, hi, lo);
                    st_u16_coh(Hbh + ((size_t)l * B_ + b) * D_ + d, hi);
                    st_u16_coh(Hbl + ((size_t)l * B_ + b) * D_ + d, lo);
                    if (l < 3) {
                        size_t xb = (((size_t)(l + 1) * 3 + (t % 3)) * B_ + b) * D_ + d;
                        st_u16_coh(Xrh + xb, hi);
                        st_u16_coh(Xrl + xb, lo);
                        FKr[(((size_t)l * 2 + (t & 1)) * B_ + b) * D_ + d] = ofk;
                    }
                    if (l == 3 && t == T_ - 1 && d >= 512)
                        out[(size_t)b * 512 + (d - 512)] = oh;
                }
            }
        }
        gbar(flags, w, ++bar);
    }
}

extern "C" void kernel_launch(void* const* d_in, const int* in_sizes, int n_in,
                              void* d_out, int out_size, void* d_ws, size_t ws_size,
                              hipStream_t stream) {
    (void)in_sizes; (void)n_in; (void)out_size;
    const float* x      = (const float*)d_in[0];
    const int*   mask   = (const int*)d_in[1];
    const float* W      = (const float*)d_in[2];
    const float* U      = (const float*)d_in[3];
    const float* bias   = (const float*)d_in[4];
    const float* gammas = (const float*)d_in[5];
    const float* betas  = (const float*)d_in[6];

    float* ws = (float*)d_ws;
    float* Y1    = ws;                                   // 4*B_*512
    float* Y2    = Y1 + (size_t)4 * B_ * 512;            // 4*B_*512
    float* pstats = Y2 + (size_t)4 * B_ * 512;           // 4*64*96*4
    float* FKr   = pstats + (size_t)4 * 64 * NWG * 4;    // 4*2*B_*D_
    unsigned* flags = (unsigned*)(FKr + (size_t)4 * 2 * B_ * D_);  // 128
    int* mcode = (int*)(flags + 128);                    // TB_
    ushort* Xbh = (ushort*)(mcode + TB_);                // TB_*D_
    ushort* Xbl = Xbh + (size_t)TB_ * D_;                // TB_*D_
    ushort* Xrh = Xbl + (size_t)TB_ * D_;                // 4*3*B_*D_
    ushort* Xrl = Xrh + (size_t)4 * 3 * B_ * D_;
    ushort* Hbh = Xrl + (size_t)4 * 3 * B_ * D_;         // 4*B_*D_
    ushort* Hbl = Hbh + (size_t)4 * B_ * D_;             // 4*B_*D_
    ushort* Uth = Hbl + (size_t)4 * B_ * D_;             // O_*D_
    ushort* Utl = Uth + (size_t)O_ * D_;
    ushort* Wth = Utl + (size_t)O_ * D_;
    ushort* Wtl = Wth + (size_t)O_ * D_;
    size_t need_bytes = ((char*)(Wtl + (size_t)O_ * D_)) - ((char*)d_ws);
    if (ws_size < need_bytes) return;

    k_prepx<<<TB_ * D_ / 4 / 256, 256, 0, stream>>>(x, Xbh, Xbl);
    k_mask<<<TB_ / 256, 256, 0, stream>>>(mask, mcode);
    k_prep<<<dim3(O_ / 64, D_ / 64), 256, 0, stream>>>(U, Uth, Utl);
    k_prep<<<dim3(O_ / 64, D_ / 64), 256, 0, stream>>>(W, Wth, Wtl);
    (void)hipMemsetAsync(Hbh, 0, sizeof(ushort) * (size_t)4 * B_ * D_ * 2, stream);
    (void)hipMemsetAsync(FKr, 0, sizeof(float) * (size_t)4 * 2 * B_ * D_, stream);
    (void)hipMemsetAsync(pstats, 0, sizeof(float) * (size_t)4 * 64 * NWG * 4, stream);
    (void)hipMemsetAsync(flags, 0, sizeof(unsigned) * 128, stream);

    k_pipe<<<NWG, 512, 0, stream>>>(x, Xbh, Xbl, Xrh, Xrl, Hbh, Hbl,
                                    Y1, Y2, pstats, FKr, flags,
                                    Uth, Utl, Wth, Wtl,
                                    gammas, betas, bias, mcode, (float*)d_out);
}

// Round 14
// 17768.005 us; speedup vs baseline: 1.5124x; 1.5124x over previous
//
#include <hip/hip_runtime.h>
#include <hip/hip_bf16.h>
#include <math.h>

#define B_   64
#define T_   256
#define DIN_ 512
#define H_   512
#define D_   1024
#define O_   1536
#define TB_  (T_*B_)
#define EPSf 1e-5f
#define NWG  96          // persistent WGs; WG w owns y-cols [16w,16w+16)
#define NSLOT (T_ + 6)   // wavefront slots: t = s - 2l

typedef short  bf16x8 __attribute__((ext_vector_type(8)));
typedef float  f32x4  __attribute__((ext_vector_type(4)));
typedef ushort u16x4  __attribute__((ext_vector_type(4)));

#define SPLIT1(f, Hm, Lm) { __hip_bfloat16 _h = __float2bfloat16(f); (Hm) = *(ushort*)&_h; \
    __hip_bfloat16 _l = __float2bfloat16((f) - __bfloat162float(_h)); (Lm) = *(ushort*)&_l; }

__device__ inline void st_f32_coh(float* p, float v) {
    __hip_atomic_store(p, v, __ATOMIC_RELAXED, __HIP_MEMORY_SCOPE_AGENT);
}
__device__ inline void st_u16_coh(ushort* p, ushort v) {
    __hip_atomic_store(p, v, __ATOMIC_RELAXED, __HIP_MEMORY_SCOPE_AGENT);
}
__device__ inline void st_f32x2_coh(float* p, float a, float b) {
    union { float f[2]; unsigned long long u; } pk;
    pk.f[0] = a; pk.f[1] = b;
    __hip_atomic_store((unsigned long long*)p, pk.u, __ATOMIC_RELAXED,
                       __HIP_MEMORY_SCOPE_AGENT);
}

// ---------------- mask codes: mcode[t*B+b] = mt | (mn<<1) ----------------
__global__ __launch_bounds__(256) void k_mask(const int* __restrict__ mask,
                                              int* __restrict__ mcode) {
    int g = blockIdx.x * 256 + threadIdx.x;
    int t = g >> 6, b = g & 63;
    int mt = mask[b * T_ + t] != 0;
    int mn = (t + 1 < T_) ? (mask[b * T_ + t + 1] != 0) : 0;
    mcode[g] = mt | (mn << 1);
}

// ---- x to bf16: Xb[t*64+b][k] = bf16(k<512 ? x[b][t][k] : 0) ----
__global__ __launch_bounds__(256) void k_prepx(const float* __restrict__ x,
                                               ushort* __restrict__ Xh) {
    int g  = blockIdx.x * 256 + threadIdx.x;
    int i4 = g * 4;
    int row = i4 >> 10;
    int k   = i4 & 1023;
    int t = row >> 6, b = row & 63;
    float4 v = make_float4(0.f, 0.f, 0.f, 0.f);
    if (k < 512) v = *(const float4*)&x[((size_t)b * T_ + t) * 512 + k];
    u16x4 h;
    __hip_bfloat16 b0 = __float2bfloat16(v.x); h[0] = *(ushort*)&b0;
    __hip_bfloat16 b1 = __float2bfloat16(v.y); h[1] = *(ushort*)&b1;
    __hip_bfloat16 b2 = __float2bfloat16(v.z); h[2] = *(ushort*)&b2;
    __hip_bfloat16 b3 = __float2bfloat16(v.w); h[3] = *(ushort*)&b3;
    *(u16x4*)&Xh[i4] = h;
}

// ---- transpose + split-bf16: Mt_hi[o][k]+Mt_lo[o][k] ≈ M[k][o]  (M is [D_][O_]) ----
__global__ __launch_bounds__(256) void k_prep(const float* __restrict__ M,
                                              ushort* __restrict__ Mt_hi,
                                              ushort* __restrict__ Mt_lo) {
    __shared__ float ls[64][65];
    int k0 = blockIdx.y * 64;
    int o0 = blockIdx.x * 64;
    int tid = threadIdx.x;
    int r = tid >> 2, cq = tid & 3;
#pragma unroll
    for (int j = 0; j < 4; ++j) {
        float4 v = *(const float4*)&M[(size_t)(k0 + r) * O_ + o0 + cq * 16 + j * 4];
        ls[r][cq * 16 + j * 4 + 0] = v.x;
        ls[r][cq * 16 + j * 4 + 1] = v.y;
        ls[r][cq * 16 + j * 4 + 2] = v.z;
        ls[r][cq * 16 + j * 4 + 3] = v.w;
    }
    __syncthreads();
    int ol = tid >> 2, kq = tid & 3;
    ushort th[16], tl[16];
#pragma unroll
    for (int j = 0; j < 16; ++j) {
        float v = ls[kq * 16 + j][ol];
        SPLIT1(v, th[j], tl[j]);
    }
    size_t base = (size_t)(o0 + ol) * D_ + k0 + kq * 16;
    *(int4*)&Mt_hi[base]     = *(int4*)&th[0];
    *(int4*)&Mt_hi[base + 8] = *(int4*)&th[8];
    *(int4*)&Mt_lo[base]     = *(int4*)&tl[0];
    *(int4*)&Mt_lo[base + 8] = *(int4*)&tl[8];
}

// ------ barrier: sc1-store protocol (verified round 8) ------
__device__ inline void gbar(unsigned* __restrict__ fl, int w, unsigned bar) {
    __syncthreads();
    asm volatile("s_waitcnt vmcnt(0)" ::: "memory");
    if (threadIdx.x == 0)
        __hip_atomic_store(&fl[w], bar, __ATOMIC_RELAXED, __HIP_MEMORY_SCOPE_AGENT);
    if (threadIdx.x < NWG) {
        while (__hip_atomic_load(&fl[threadIdx.x], __ATOMIC_RELAXED,
                                 __HIP_MEMORY_SCOPE_AGENT) < bar)
            __builtin_amdgcn_s_sleep(2);
    }
    __syncthreads();
    __builtin_amdgcn_fence(__ATOMIC_ACQUIRE, "agent");
}

// ================= 4-layer wavefront pipeline (3-phase slots) =================
// 96 WGs x 256 thr; WG w owns cols [16w,16w+16); wave wv owns rows [16wv,16wv+16).
// slot s: layer l does step t = s-2l. A-side matvec operands are bf16 (hi only);
// B-side (U/W) stays split hi+lo; gate state stays fp32 in registers.
__global__ __launch_bounds__(256, 1) void k_pipe(
        const float* __restrict__ x,
        const ushort* __restrict__ Xbh,
        ushort* __restrict__ Xrh,
        ushort* __restrict__ Hbh,
        float* __restrict__ Y1, float* __restrict__ Y2,
        float* __restrict__ pstats, float* __restrict__ finals,
        unsigned* __restrict__ flags,
        const ushort* __restrict__ Uth, const ushort* __restrict__ Utl,
        const ushort* __restrict__ Wth, const ushort* __restrict__ Wtl,
        const float* __restrict__ gam, const float* __restrict__ bet,
        const float* __restrict__ bias,
        const int* __restrict__ mcode, float* __restrict__ out) {
    __shared__ __hip_bfloat16 lds[4 * 16 * 1024];   // [U_hi|U_lo|W_hi|W_lo] 32KB each
    const int w = blockIdx.x;
    const int tid = threadIdx.x;
    const int lane = tid & 63;
    const int wv = tid >> 6;
    const int lr = lane & 15;
    const int lg = lane >> 4;
    const int c0 = w * 16;
    const int b0 = wv * 16;

    // stage U/W tiles (cols c0..c0+16) into LDS, XOR-swizzled
    {
        int cl = tid >> 4, kc = tid & 15;
        const ushort* srcs0 = Uth + (size_t)(c0 + cl) * D_ + kc * 64;
        const ushort* srcs1 = Utl + (size_t)(c0 + cl) * D_ + kc * 64;
        const ushort* srcs2 = Wth + (size_t)(c0 + cl) * D_ + kc * 64;
        const ushort* srcs3 = Wtl + (size_t)(c0 + cl) * D_ + kc * 64;
        char* base = (char*)lds;
#pragma unroll
        for (int j = 0; j < 8; ++j) {
            int k = kc * 64 + j * 8;
            int off = (cl * 2048 + k * 2) ^ ((cl & 7) << 4);
            *(int4*)(base + off)           = *(const int4*)(srcs0 + j * 8);
            *(int4*)(base + 32768 + off)   = *(const int4*)(srcs1 + j * 8);
            *(int4*)(base + 65536 + off)   = *(const int4*)(srcs2 + j * 8);
            *(int4*)(base + 98304 + off)   = *(const int4*)(srcs3 + j * 8);
        }
    }
    __syncthreads();

    const int d = c0 + lr;
    const bool gate_w = (w < 64);
    const bool tanh_w = (w >= 32 && w < 64);
    float g0d = 0.f, g1d = 0.f, cd = 0.f, g0e = 0.f, g1e = 0.f, ce = 0.f;
    if (gate_w) {
        g0d = gam[d]; g1d = gam[O_ + d];
        cd  = bet[d] + bet[O_ + d] + bias[d];
    }
    if (tanh_w) {
        int e = d + 512;
        g0e = gam[e]; g1e = gam[O_ + e];
        ce  = bet[e] + bet[O_ + e] + bias[e];
    }
    int brow[4];
#pragma unroll
    for (int j = 0; j < 4; ++j) brow[j] = b0 + lg * 4 + j;

    // per-layer per-row register state (gate waves) -- all fp32
    float h1r[4][4] = {}, fk1r[4][4] = {};
    float oh_d1[4][4] = {}, oh_d2[4][4] = {}, fkp_d1[4][4] = {};
    f32x4 acc1[4], acc2[4];

    unsigned bar = 0;
    for (int s = 0; s < NSLOT; ++s) {
        // ---------------- phase A: matvecs + partial stats ----------------
#pragma unroll
        for (int l = 0; l < 4; ++l) {
            int t = s - 2 * l;
            bool act = (t >= 0) && (t < T_);
            if (!act) continue;
            const ushort* xsh;
            if (l == 0) {
                xsh = Xbh + ((size_t)t * B_ + b0 + lr) * D_;
            } else {
                xsh = Xrh + (((size_t)l * 3 + (t % 3)) * B_ + b0 + lr) * D_;
            }
            const ushort* hsh = Hbh + ((size_t)l * B_ + b0 + lr) * D_;
            const char* lb = (const char*)lds;
            f32x4 a10 = {0,0,0,0}, a11 = {0,0,0,0};
            f32x4 a20 = {0,0,0,0}, a21 = {0,0,0,0};
#pragma unroll 4
            for (int kc = 0; kc < 32; ++kc) {
                int k = kc * 32 + lg * 8;
                int off = (lr * 2048 + k * 2) ^ ((lr & 7) << 4);
                bf16x8 xa = *(const bf16x8*)(xsh + k);
                bf16x8 ha = *(const bf16x8*)(hsh + k);
                bf16x8 ubh = *(const bf16x8*)(lb + off);
                bf16x8 ubl = *(const bf16x8*)(lb + 32768 + off);
                bf16x8 wbh = *(const bf16x8*)(lb + 65536 + off);
                bf16x8 wbl = *(const bf16x8*)(lb + 98304 + off);
                a10 = __builtin_amdgcn_mfma_f32_16x16x32_bf16(xa, wbh, a10, 0, 0, 0);
                a11 = __builtin_amdgcn_mfma_f32_16x16x32_bf16(xa, wbl, a11, 0, 0, 0);
                a20 = __builtin_amdgcn_mfma_f32_16x16x32_bf16(ha, ubh, a20, 0, 0, 0);
                a21 = __builtin_amdgcn_mfma_f32_16x16x32_bf16(ha, ubl, a21, 0, 0, 0);
            }
            acc1[l] = a10 + a11;
            acc2[l] = a20 + a21;
            // per-row partial stats -> pstats[(l,b,w)] (no contention)
#pragma unroll
            for (int j = 0; j < 4; ++j) {
                float s1 = acc1[l][j], q1 = s1 * s1;
                float s2 = acc2[l][j], q2 = s2 * s2;
#pragma unroll
                for (int m = 1; m < 16; m <<= 1) {
                    s1 += __shfl_xor(s1, m); q1 += __shfl_xor(q1, m);
                    s2 += __shfl_xor(s2, m); q2 += __shfl_xor(q2, m);
                }
                if (lr == 0) {
                    float* sp = &pstats[(((size_t)l * 64 + brow[j]) * NWG + w) * 4];
                    st_f32x2_coh(sp, s1, q1);
                    st_f32x2_coh(sp + 2, s2, q2);
                }
            }
            // export tanh-partner cols (w>=64)
            if (w >= 64) {
                int cexp = c0 + lr - 1024;
#pragma unroll
                for (int j = 0; j < 4; ++j) {
                    st_f32_coh(&Y1[((size_t)l * B_ + brow[j]) * 512 + cexp], acc1[l][j]);
                    st_f32_coh(&Y2[((size_t)l * B_ + brow[j]) * 512 + cexp], acc2[l][j]);
                }
            }
        }
        gbar(flags, w, ++bar);

        // ---------------- phase B: stats reduce (pair = w + 96*wv) ----------------
        {
            int pair = w + NWG * wv;
            if (pair < 256) {
                const float* pp = &pstats[(size_t)pair * NWG * 4];
                float s1 = 0.f, q1 = 0.f, s2 = 0.f, q2 = 0.f;
                if (lane < 32) {
#pragma unroll
                    for (int i = 0; i < 3; ++i) {
                        float4 v = *(const float4*)(pp + (lane + i * 32) * 4);
                        s1 += v.x; q1 += v.y; s2 += v.z; q2 += v.w;
                    }
                }
#pragma unroll
                for (int m = 1; m < 32; m <<= 1) {
                    s1 += __shfl_xor(s1, m); q1 += __shfl_xor(q1, m);
                    s2 += __shfl_xor(s2, m); q2 += __shfl_xor(q2, m);
                }
                if (lane == 0) {
                    float m1 = s1 * (1.f / O_);
                    float v1 = q1 * (1.f / O_) - m1 * m1;
                    float i1 = 1.f / (sqrtf(v1 + EPSf) + EPSf);
                    float m2 = s2 * (1.f / O_);
                    float v2 = q2 * (1.f / O_) - m2 * m2;
                    float i2 = 1.f / (sqrtf(v2 + EPSf) + EPSf);
                    st_f32x2_coh(&finals[(size_t)pair * 4], m1, i1);
                    st_f32x2_coh(&finals[(size_t)pair * 4 + 2], m2, i2);
                }
            }
        }
        gbar(flags, w, ++bar);

        // ---------------- phase C: gating (descending layers) ----------------
        if (gate_w) {
#pragma unroll
            for (int li = 0; li < 4; ++li) {
                const int l = 3 - li;
                const int lp = (l > 0) ? l - 1 : 0;
                int t = s - 2 * l;
                bool act = (t >= 0) && (t < T_);
                float ohn[4], ofkn[4];
                if (act) {
                    int4 mc4 = *(const int4*)&mcode[t * B_ + b0 + lg * 4];
                    int mcarr[4] = {mc4.x, mc4.y, mc4.z, mc4.w};
#pragma unroll
                    for (int j = 0; j < 4; ++j) {
                        int b = brow[j];
                        float4 sv = *(const float4*)&finals[((size_t)l * 64 + b) * 4];
                        float m1 = sv.x, i1 = sv.y, m2 = sv.z, i2 = sv.w;
                        float y1 = acc1[l][j], y2 = acc2[l][j];
                        float td = g0d * (y1 - m1) * i1 + g1d * (y2 - m2) * i2 + cd;
                        float fkc = fminf(fmaxf(0.2f * td + 0.5f, 0.f), 1.f);
                        float hpad = 0.f;
                        if (tanh_w) {
                            float y1e = Y1[((size_t)l * B_ + b) * 512 + (d - 512)];
                            float y2e = Y2[((size_t)l * B_ + b) * 512 + (d - 512)];
                            float te = g0e * (y1e - m1) * i1 + g1e * (y2e - m2) * i2 + ce;
                            hpad = tanhf(te);
                        }
                        float xt;
                        if (l == 0)
                            xt = (d < 512) ? x[((size_t)b * T_ + t) * 512 + d] : 0.f;
                        else
                            xt = oh_d2[lp][j];
                        float fkp = (l > 0 && t + 1 < T_) ? fkp_d1[lp][j] : 0.f;
                        float hc = (1.f - fkc) * xt + fkc * hpad;
                        float h  = fkp * h1r[l][j] + (1.f - fkp) * hc;
                        float fk = fkp + (1.f - fkp) * fkc;
                        int mt = mcarr[j] & 1, mn = (mcarr[j] >> 1) & 1;
                        if (mt && !mn) fk = 0.f;
                        float oh  = mt ? h  : h1r[l][j];
                        float ofk = mt ? fk : fk1r[l][j];
                        h1r[l][j] = oh; fk1r[l][j] = ofk;
                        __hip_bfloat16 hb = __float2bfloat16(oh);
                        ushort hi = *(ushort*)&hb;
                        st_u16_coh(Hbh + ((size_t)l * B_ + b) * D_ + d, hi);
                        if (l < 3) {
                            size_t xb = (((size_t)(l + 1) * 3 + (t % 3)) * B_ + b) * D_ + d;
                            st_u16_coh(Xrh + xb, hi);
                        }
                        if (l == 3 && t == T_ - 1 && d >= 512)
                            out[(size_t)b * 512 + (d - 512)] = oh;
                        ohn[j] = oh; ofkn[j] = ofk;
                    }
                }
#pragma unroll
                for (int j = 0; j < 4; ++j) {
                    oh_d2[l][j] = oh_d1[l][j];
                    if (act) { oh_d1[l][j] = ohn[j]; fkp_d1[l][j] = ofkn[j]; }
                }
            }
        }
        gbar(flags, w, ++bar);
    }
}

extern "C" void kernel_launch(void* const* d_in, const int* in_sizes, int n_in,
                              void* d_out, int out_size, void* d_ws, size_t ws_size,
                              hipStream_t stream) {
    (void)in_sizes; (void)n_in; (void)out_size;
    const float* x      = (const float*)d_in[0];
    const int*   mask   = (const int*)d_in[1];
    const float* W      = (const float*)d_in[2];
    const float* U      = (const float*)d_in[3];
    const float* bias   = (const float*)d_in[4];
    const float* gammas = (const float*)d_in[5];
    const float* betas  = (const float*)d_in[6];

    float* ws = (float*)d_ws;
    float* Y1    = ws;                                   // 4*B_*512
    float* Y2    = Y1 + (size_t)4 * B_ * 512;            // 4*B_*512
    float* pstats = Y2 + (size_t)4 * B_ * 512;           // 4*64*96*4
    float* finals = pstats + (size_t)4 * 64 * NWG * 4;   // 256*4
    unsigned* flags = (unsigned*)(finals + 256 * 4);     // 128
    int* mcode = (int*)(flags + 128);                    // TB_
    ushort* Xbh = (ushort*)(mcode + TB_);                // TB_*D_
    ushort* Xrh = Xbh + (size_t)TB_ * D_;                // 4*3*B_*D_
    ushort* Hbh = Xrh + (size_t)4 * 3 * B_ * D_;         // 4*B_*D_
    ushort* Uth = Hbh + (size_t)4 * B_ * D_;             // O_*D_
    ushort* Utl = Uth + (size_t)O_ * D_;
    ushort* Wth = Utl + (size_t)O_ * D_;
    ushort* Wtl = Wth + (size_t)O_ * D_;
    size_t need_bytes = ((char*)(Wtl + (size_t)O_ * D_)) - ((char*)d_ws);
    if (ws_size < need_bytes) return;

    k_prepx<<<TB_ * D_ / 4 / 256, 256, 0, stream>>>(x, Xbh);
    k_mask<<<TB_ / 256, 256, 0, stream>>>(mask, mcode);
    k_prep<<<dim3(O_ / 64, D_ / 64), 256, 0, stream>>>(U, Uth, Utl);
    k_prep<<<dim3(O_ / 64, D_ / 64), 256, 0, stream>>>(W, Wth, Wtl);
    (void)hipMemsetAsync(Hbh, 0, sizeof(ushort) * (size_t)4 * B_ * D_, stream);
    (void)hipMemsetAsync(pstats, 0, sizeof(float) * (size_t)4 * 64 * NWG * 4, stream);
    (void)hipMemsetAsync(flags, 0, sizeof(unsigned) * 128, stream);

    k_pipe<<<NWG, 256, 0, stream>>>(x, Xbh, Xrh, Hbh,
                                    Y1, Y2, pstats, finals, flags,
                                    Uth, Utl, Wth, Wtl,
                                    gammas, betas, bias, mcode, (float*)d_out);
}

// Round 15
// 15315.483 us; speedup vs baseline: 1.7545x; 1.1601x over previous
//
#include <hip/hip_runtime.h>
#include <hip/hip_bf16.h>
#include <math.h>

#define B_   64
#define T_   256
#define DIN_ 512
#define H_   512
#define D_   1024
#define O_   1536
#define TB_  (T_*B_)
#define EPSf 1e-5f
#define NWG  96          // col-WGs per domain; WG w owns y-cols [16w,16w+16)
#define NSLOT (T_ + 6)   // wavefront slots: t = s - 2l

typedef short  bf16x8 __attribute__((ext_vector_type(8)));
typedef float  f32x4  __attribute__((ext_vector_type(4)));
typedef ushort u16x4  __attribute__((ext_vector_type(4)));
typedef unsigned long long ull;

#define SPLIT1(f, Hm, Lm) { __hip_bfloat16 _h = __float2bfloat16(f); (Hm) = *(ushort*)&_h; \
    __hip_bfloat16 _l = __float2bfloat16((f) - __bfloat162float(_h)); (Lm) = *(ushort*)&_l; }

__device__ inline void st_f32_coh(float* p, float v) {
    __hip_atomic_store(p, v, __ATOMIC_RELAXED, __HIP_MEMORY_SCOPE_AGENT);
}
__device__ inline void st_u16_coh(ushort* p, ushort v) {
    __hip_atomic_store(p, v, __ATOMIC_RELAXED, __HIP_MEMORY_SCOPE_AGENT);
}
__device__ inline void st_u32_coh(unsigned* p, unsigned v) {
    __hip_atomic_store(p, v, __ATOMIC_RELAXED, __HIP_MEMORY_SCOPE_AGENT);
}
__device__ inline void st_f32x2_coh(float* p, float a, float b) {
    union { float f[2]; ull u; } pk;
    pk.f[0] = a; pk.f[1] = b;
    __hip_atomic_store((ull*)p, pk.u, __ATOMIC_RELAXED, __HIP_MEMORY_SCOPE_AGENT);
}

// ---------------- mask codes: mcode[t*B+b] = mt | (mn<<1) ----------------
__global__ __launch_bounds__(256) void k_mask(const int* __restrict__ mask,
                                              int* __restrict__ mcode) {
    int g = blockIdx.x * 256 + threadIdx.x;
    int t = g >> 6, b = g & 63;
    int mt = mask[b * T_ + t] != 0;
    int mn = (t + 1 < T_) ? (mask[b * T_ + t + 1] != 0) : 0;
    mcode[g] = mt | (mn << 1);
}

// ---- x to bf16: Xb[t*64+b][k] = bf16(k<512 ? x[b][t][k] : 0) ----
__global__ __launch_bounds__(256) void k_prepx(const float* __restrict__ x,
                                               ushort* __restrict__ Xh) {
    int g  = blockIdx.x * 256 + threadIdx.x;
    int i4 = g * 4;
    int row = i4 >> 10;
    int k   = i4 & 1023;
    int t = row >> 6, b = row & 63;
    float4 v = make_float4(0.f, 0.f, 0.f, 0.f);
    if (k < 512) v = *(const float4*)&x[((size_t)b * T_ + t) * 512 + k];
    u16x4 h;
    __hip_bfloat16 b0 = __float2bfloat16(v.x); h[0] = *(ushort*)&b0;
    __hip_bfloat16 b1 = __float2bfloat16(v.y); h[1] = *(ushort*)&b1;
    __hip_bfloat16 b2 = __float2bfloat16(v.z); h[2] = *(ushort*)&b2;
    __hip_bfloat16 b3 = __float2bfloat16(v.w); h[3] = *(ushort*)&b3;
    *(u16x4*)&Xh[i4] = h;
}

// ---- transpose + split-bf16: Mt_hi[o][k]+Mt_lo[o][k] ≈ M[k][o]  (M is [D_][O_]) ----
__global__ __launch_bounds__(256) void k_prep(const float* __restrict__ M,
                                              ushort* __restrict__ Mt_hi,
                                              ushort* __restrict__ Mt_lo) {
    __shared__ float ls[64][65];
    int k0 = blockIdx.y * 64;
    int o0 = blockIdx.x * 64;
    int tid = threadIdx.x;
    int r = tid >> 2, cq = tid & 3;
#pragma unroll
    for (int j = 0; j < 4; ++j) {
        float4 v = *(const float4*)&M[(size_t)(k0 + r) * O_ + o0 + cq * 16 + j * 4];
        ls[r][cq * 16 + j * 4 + 0] = v.x;
        ls[r][cq * 16 + j * 4 + 1] = v.y;
        ls[r][cq * 16 + j * 4 + 2] = v.z;
        ls[r][cq * 16 + j * 4 + 3] = v.w;
    }
    __syncthreads();
    int ol = tid >> 2, kq = tid & 3;
    ushort th[16], tl[16];
#pragma unroll
    for (int j = 0; j < 16; ++j) {
        float v = ls[kq * 16 + j][ol];
        SPLIT1(v, th[j], tl[j]);
    }
    size_t base = (size_t)(o0 + ol) * D_ + k0 + kq * 16;
    *(int4*)&Mt_hi[base]     = *(int4*)&th[0];
    *(int4*)&Mt_hi[base + 8] = *(int4*)&th[8];
    *(int4*)&Mt_lo[base]     = *(int4*)&tl[0];
    *(int4*)&Mt_lo[base + 8] = *(int4*)&tl[8];
}

// ------ barrier: sc1-store protocol (verified round 8); per-domain flags ------
__device__ inline void gbar(unsigned* __restrict__ fl, int w, unsigned bar) {
    __syncthreads();
    asm volatile("s_waitcnt vmcnt(0)" ::: "memory");
    if (threadIdx.x == 0)
        __hip_atomic_store(&fl[w], bar, __ATOMIC_RELAXED, __HIP_MEMORY_SCOPE_AGENT);
    if (threadIdx.x < NWG) {
        while (__hip_atomic_load(&fl[threadIdx.x], __ATOMIC_RELAXED,
                                 __HIP_MEMORY_SCOPE_AGENT) < bar)
            __builtin_amdgcn_s_sleep(2);
    }
    __syncthreads();
    __builtin_amdgcn_fence(__ATOMIC_ACQUIRE, "agent");
}

// ============ 4-layer wavefront pipeline, 2 batch domains ============
// 192 WGs: dom = bx/96 owns rows [32dom,32dom+32); w = bx%96 owns cols [16w,+16).
// waves: rt = wv&1 (16-row tile), kh = wv>>1 (K-half); partials combined in LDS.
// slot: A | bar | B(reduce+tag) ~~tag-sync~~ C(gate) | bar.  2 device barriers.
__global__ __launch_bounds__(256, 1) void k_pipe(
        const float* __restrict__ x,
        const ushort* __restrict__ Xbh,
        ushort* __restrict__ Xrh,
        ushort* __restrict__ Hbh,
        float* __restrict__ Y1, float* __restrict__ Y2,
        float* __restrict__ pstats, float* __restrict__ finals,
        unsigned* __restrict__ ftag, unsigned* __restrict__ flags,
        const ushort* __restrict__ Uth, const ushort* __restrict__ Utl,
        const ushort* __restrict__ Wth, const ushort* __restrict__ Wtl,
        const float* __restrict__ gam, const float* __restrict__ bet,
        const float* __restrict__ bias,
        const int* __restrict__ mcode, float* __restrict__ out) {
    __shared__ __hip_bfloat16 lds[4 * 16 * 1024];   // [U_hi|U_lo|W_hi|W_lo] 32KB each
    __shared__ f32x4 ldsc[2][64][2];                // K-half partial combine
    const int bx = blockIdx.x;
    const int dom = bx / NWG;
    const int w   = bx % NWG;
    const int tid = threadIdx.x;
    const int lane = tid & 63;
    const int wv = tid >> 6;
    const int rt = wv & 1;             // row tile within domain
    const int kh = wv >> 1;            // K half
    const int lr = lane & 15;
    const int lg = lane >> 4;
    const int c0 = w * 16;
    const int br0 = dom * 32 + rt * 16;     // global row base of this wave's tile
    unsigned* fl = flags + dom * 128;
    float* pst   = pstats + (size_t)dom * 4 * 32 * NWG * 4;
    float* fin   = finals + (size_t)dom * 128 * 4;
    unsigned* ft = ftag + (size_t)dom * 128;

    // stage U/W tiles (cols c0..c0+16) into LDS, XOR-swizzled
    {
        int cl = tid >> 4, kc = tid & 15;
        const ushort* srcs0 = Uth + (size_t)(c0 + cl) * D_ + kc * 64;
        const ushort* srcs1 = Utl + (size_t)(c0 + cl) * D_ + kc * 64;
        const ushort* srcs2 = Wth + (size_t)(c0 + cl) * D_ + kc * 64;
        const ushort* srcs3 = Wtl + (size_t)(c0 + cl) * D_ + kc * 64;
        char* base = (char*)lds;
#pragma unroll
        for (int j = 0; j < 8; ++j) {
            int k = kc * 64 + j * 8;
            int off = (cl * 2048 + k * 2) ^ ((cl & 7) << 4);
            *(int4*)(base + off)           = *(const int4*)(srcs0 + j * 8);
            *(int4*)(base + 32768 + off)   = *(const int4*)(srcs1 + j * 8);
            *(int4*)(base + 65536 + off)   = *(const int4*)(srcs2 + j * 8);
            *(int4*)(base + 98304 + off)   = *(const int4*)(srcs3 + j * 8);
        }
    }
    __syncthreads();

    const int d = c0 + lr;
    const bool gate_w = (w < 64);
    const bool tanh_w = (w >= 32 && w < 64);
    float g0d = 0.f, g1d = 0.f, cd = 0.f, g0e = 0.f, g1e = 0.f, ce = 0.f;
    if (gate_w) {
        g0d = gam[d]; g1d = gam[O_ + d];
        cd  = bet[d] + bet[O_ + d] + bias[d];
    }
    if (tanh_w) {
        int e = d + 512;
        g0e = gam[e]; g1e = gam[O_ + e];
        ce  = bet[e] + bet[O_ + e] + bias[e];
    }

    // gate-wave register state (waves wv<2 only; wave wv owns rows dom*32+wv*16..+16)
    float h1r[4][4] = {}, fk1r[4][4] = {};
    float oh_d1[4][4] = {}, oh_d2[4][4] = {}, fkp_d1[4][4] = {};
    f32x4 acc1[4], acc2[4];

    unsigned bar = 0;
    for (int s = 0; s < NSLOT; ++s) {
        // ---------------- phase A: matvecs (K-split) + partial stats ----------------
#pragma unroll
        for (int l = 0; l < 4; ++l) {
            int t = s - 2 * l;
            bool act = (t >= 0) && (t < T_);
            f32x4 p1 = {0,0,0,0}, p2 = {0,0,0,0};
            if (act) {
                const ushort* xsh;
                if (l == 0) {
                    xsh = Xbh + ((size_t)t * B_ + br0 + lr) * D_ + kh * 512;
                } else {
                    xsh = Xrh + (((size_t)l * 3 + (t % 3)) * B_ + br0 + lr) * D_ + kh * 512;
                }
                const ushort* hsh = Hbh + ((size_t)l * B_ + br0 + lr) * D_ + kh * 512;
                const char* lb = (const char*)lds;
                f32x4 a10 = {0,0,0,0}, a11 = {0,0,0,0};
                f32x4 a20 = {0,0,0,0}, a21 = {0,0,0,0};
#pragma unroll 4
                for (int kc = 0; kc < 16; ++kc) {
                    int kloc = kc * 32 + lg * 8;
                    int kglob = kh * 512 + kloc;
                    int off = (lr * 2048 + kglob * 2) ^ ((lr & 7) << 4);
                    bf16x8 xa = *(const bf16x8*)(xsh + kloc);
                    bf16x8 ha = *(const bf16x8*)(hsh + kloc);
                    bf16x8 ubh = *(const bf16x8*)(lb + off);
                    bf16x8 ubl = *(const bf16x8*)(lb + 32768 + off);
                    bf16x8 wbh = *(const bf16x8*)(lb + 65536 + off);
                    bf16x8 wbl = *(const bf16x8*)(lb + 98304 + off);
                    a10 = __builtin_amdgcn_mfma_f32_16x16x32_bf16(xa, wbh, a10, 0, 0, 0);
                    a11 = __builtin_amdgcn_mfma_f32_16x16x32_bf16(xa, wbl, a11, 0, 0, 0);
                    a20 = __builtin_amdgcn_mfma_f32_16x16x32_bf16(ha, ubh, a20, 0, 0, 0);
                    a21 = __builtin_amdgcn_mfma_f32_16x16x32_bf16(ha, ubl, a21, 0, 0, 0);
                }
                p1 = a10 + a11;
                p2 = a20 + a21;
                if (kh == 1) { ldsc[rt][lane][0] = p1; ldsc[rt][lane][1] = p2; }
            }
            __syncthreads();
            if (act && kh == 0) {
                f32x4 o1 = ldsc[rt][lane][0], o2 = ldsc[rt][lane][1];
                acc1[l] = p1 + o1;
                acc2[l] = p2 + o2;
                // per-row partial stats -> pstats[(l,lrow,w)] (no contention)
#pragma unroll
                for (int j = 0; j < 4; ++j) {
                    float s1 = acc1[l][j], q1 = s1 * s1;
                    float s2 = acc2[l][j], q2 = s2 * s2;
#pragma unroll
                    for (int m = 1; m < 16; m <<= 1) {
                        s1 += __shfl_xor(s1, m); q1 += __shfl_xor(q1, m);
                        s2 += __shfl_xor(s2, m); q2 += __shfl_xor(q2, m);
                    }
                    if (lr == 0) {
                        int lrow = rt * 16 + lg * 4 + j;
                        float* sp = &pst[(((size_t)l * 32 + lrow) * NWG + w) * 4];
                        st_f32x2_coh(sp, s1, q1);
                        st_f32x2_coh(sp + 2, s2, q2);
                    }
                }
                // export tanh-partner cols (w>=64)
                if (w >= 64) {
                    int cexp = c0 + lr - 1024;
#pragma unroll
                    for (int j = 0; j < 4; ++j) {
                        int b = br0 + lg * 4 + j;
                        st_f32_coh(&Y1[((size_t)l * B_ + b) * 512 + cexp], acc1[l][j]);
                        st_f32_coh(&Y2[((size_t)l * B_ + b) * 512 + cexp], acc2[l][j]);
                    }
                }
            }
            __syncthreads();
        }
        gbar(fl, w, ++bar);

        // ------- phase B: stats reduce (pair = w + 96*wv, wv<2) + tag -------
        if (wv < 2) {
            int pair = w + NWG * wv;
            if (pair < 128) {
                const float* pp = &pst[(size_t)pair * NWG * 4];
                float s1 = 0.f, q1 = 0.f, s2 = 0.f, q2 = 0.f;
                if (lane < 32) {
#pragma unroll
                    for (int i = 0; i < 3; ++i) {
                        float4 v = *(const float4*)(pp + (lane + i * 32) * 4);
                        s1 += v.x; q1 += v.y; s2 += v.z; q2 += v.w;
                    }
                }
#pragma unroll
                for (int m = 1; m < 32; m <<= 1) {
                    s1 += __shfl_xor(s1, m); q1 += __shfl_xor(q1, m);
                    s2 += __shfl_xor(s2, m); q2 += __shfl_xor(q2, m);
                }
                if (lane == 0) {
                    float m1 = s1 * (1.f / O_);
                    float v1 = q1 * (1.f / O_) - m1 * m1;
                    float i1 = 1.f / (sqrtf(v1 + EPSf) + EPSf);
                    float m2 = s2 * (1.f / O_);
                    float v2 = q2 * (1.f / O_) - m2 * m2;
                    float i2 = 1.f / (sqrtf(v2 + EPSf) + EPSf);
                    st_f32x2_coh(&fin[(size_t)pair * 4], m1, i1);
                    st_f32x2_coh(&fin[(size_t)pair * 4 + 2], m2, i2);
                    asm volatile("s_waitcnt vmcnt(0)" ::: "memory");
                    st_u32_coh(&ft[pair], (unsigned)(s + 1));
                }
            }
        }

        // ------- phase C: gating (waves wv<2; tag-synced finals) -------
        if (gate_w && wv < 2) {
#pragma unroll
            for (int li = 0; li < 4; ++li) {
                const int l = 3 - li;
                const int lp = (l > 0) ? l - 1 : 0;
                int t = s - 2 * l;
                bool act = (t >= 0) && (t < T_);
                float ohn[4], ofkn[4];
                if (act) {
                    int b_base = dom * 32 + wv * 16 + lg * 4;
                    int4 mc4 = *(const int4*)&mcode[t * B_ + b_base];
                    int mcarr[4] = {mc4.x, mc4.y, mc4.z, mc4.w};
#pragma unroll
                    for (int j = 0; j < 4; ++j) {
                        int b = b_base + j;
                        int lrow = wv * 16 + lg * 4 + j;
                        int pair = l * 32 + lrow;
                        while (__hip_atomic_load(&ft[pair], __ATOMIC_RELAXED,
                                                 __HIP_MEMORY_SCOPE_AGENT) < (unsigned)(s + 1))
                            __builtin_amdgcn_s_sleep(1);
                        union { ull u[2]; float f[4]; } fv;
                        fv.u[0] = __hip_atomic_load((ull*)&fin[(size_t)pair * 4],
                                                    __ATOMIC_RELAXED, __HIP_MEMORY_SCOPE_AGENT);
                        fv.u[1] = __hip_atomic_load((ull*)&fin[(size_t)pair * 4 + 2],
                                                    __ATOMIC_RELAXED, __HIP_MEMORY_SCOPE_AGENT);
                        float m1 = fv.f[0], i1 = fv.f[1], m2 = fv.f[2], i2 = fv.f[3];
                        float y1 = acc1[l][j], y2 = acc2[l][j];
                        float td = g0d * (y1 - m1) * i1 + g1d * (y2 - m2) * i2 + cd;
                        float fkc = fminf(fmaxf(0.2f * td + 0.5f, 0.f), 1.f);
                        float hpad = 0.f;
                        if (tanh_w) {
                            float y1e = Y1[((size_t)l * B_ + b) * 512 + (d - 512)];
                            float y2e = Y2[((size_t)l * B_ + b) * 512 + (d - 512)];
                            float te = g0e * (y1e - m1) * i1 + g1e * (y2e - m2) * i2 + ce;
                            hpad = tanhf(te);
                        }
                        float xt;
                        if (l == 0)
                            xt = (d < 512) ? x[((size_t)b * T_ + t) * 512 + d] : 0.f;
                        else
                            xt = oh_d2[lp][j];
                        float fkp = (l > 0 && t + 1 < T_) ? fkp_d1[lp][j] : 0.f;
                        float hc = (1.f - fkc) * xt + fkc * hpad;
                        float h  = fkp * h1r[l][j] + (1.f - fkp) * hc;
                        float fk = fkp + (1.f - fkp) * fkc;
                        int mt = mcarr[j] & 1, mn = (mcarr[j] >> 1) & 1;
                        if (mt && !mn) fk = 0.f;
                        float oh  = mt ? h  : h1r[l][j];
                        float ofk = mt ? fk : fk1r[l][j];
                        h1r[l][j] = oh; fk1r[l][j] = ofk;
                        __hip_bfloat16 hb = __float2bfloat16(oh);
                        ushort hi = *(ushort*)&hb;
                        st_u16_coh(Hbh + ((size_t)l * B_ + b) * D_ + d, hi);
                        if (l < 3) {
                            size_t xb = (((size_t)(l + 1) * 3 + (t % 3)) * B_ + b) * D_ + d;
                            st_u16_coh(Xrh + xb, hi);
                        }
                        if (l == 3 && t == T_ - 1 && d >= 512)
                            out[(size_t)b * 512 + (d - 512)] = oh;
                        ohn[j] = oh; ofkn[j] = ofk;
                    }
                }
#pragma unroll
                for (int j = 0; j < 4; ++j) {
                    oh_d2[l][j] = oh_d1[l][j];
                    if (act) { oh_d1[l][j] = ohn[j]; fkp_d1[l][j] = ofkn[j]; }
                }
            }
        }
        gbar(fl, w, ++bar);
    }
}

extern "C" void kernel_launch(void* const* d_in, const int* in_sizes, int n_in,
                              void* d_out, int out_size, void* d_ws, size_t ws_size,
                              hipStream_t stream) {
    (void)in_sizes; (void)n_in; (void)out_size;
    const float* x      = (const float*)d_in[0];
    const int*   mask   = (const int*)d_in[1];
    const float* W      = (const float*)d_in[2];
    const float* U      = (const float*)d_in[3];
    const float* bias   = (const float*)d_in[4];
    const float* gammas = (const float*)d_in[5];
    const float* betas  = (const float*)d_in[6];

    float* ws = (float*)d_ws;
    float* Y1    = ws;                                     // 4*B_*512
    float* Y2    = Y1 + (size_t)4 * B_ * 512;              // 4*B_*512
    float* pstats = Y2 + (size_t)4 * B_ * 512;             // 2*4*32*96*4
    float* finals = pstats + (size_t)2 * 4 * 32 * NWG * 4; // 2*128*4
    unsigned* ftag  = (unsigned*)(finals + 2 * 128 * 4);   // 2*128
    unsigned* flags = ftag + 2 * 128;                      // 256
    int* mcode = (int*)(flags + 256);                      // TB_
    ushort* Xbh = (ushort*)(mcode + TB_);                  // TB_*D_
    ushort* Xrh = Xbh + (size_t)TB_ * D_;                  // 4*3*B_*D_
    ushort* Hbh = Xrh + (size_t)4 * 3 * B_ * D_;           // 4*B_*D_
    ushort* Uth = Hbh + (size_t)4 * B_ * D_;               // O_*D_
    ushort* Utl = Uth + (size_t)O_ * D_;
    ushort* Wth = Utl + (size_t)O_ * D_;
    ushort* Wtl = Wth + (size_t)O_ * D_;
    size_t need_bytes = ((char*)(Wtl + (size_t)O_ * D_)) - ((char*)d_ws);
    if (ws_size < need_bytes) return;

    k_prepx<<<TB_ * D_ / 4 / 256, 256, 0, stream>>>(x, Xbh);
    k_mask<<<TB_ / 256, 256, 0, stream>>>(mask, mcode);
    k_prep<<<dim3(O_ / 64, D_ / 64), 256, 0, stream>>>(U, Uth, Utl);
    k_prep<<<dim3(O_ / 64, D_ / 64), 256, 0, stream>>>(W, Wth, Wtl);
    (void)hipMemsetAsync(Hbh, 0, sizeof(ushort) * (size_t)4 * B_ * D_, stream);
    (void)hipMemsetAsync(pstats, 0, sizeof(float) * (size_t)2 * 4 * 32 * NWG * 4, stream);
    (void)hipMemsetAsync(ftag, 0, sizeof(unsigned) * 2 * 128, stream);
    (void)hipMemsetAsync(flags, 0, sizeof(unsigned) * 256, stream);

    k_pipe<<<2 * NWG, 256, 0, stream>>>(x, Xbh, Xrh, Hbh,
                                        Y1, Y2, pstats, finals, ftag, flags,
                                        Uth, Utl, Wth, Wtl,
                                        gammas, betas, bias, mcode, (float*)d_out);
}

// Round 16
// 15154.939 us; speedup vs baseline: 1.7731x; 1.0106x over previous
//
#include <hip/hip_runtime.h>
#include <hip/hip_bf16.h>
#include <math.h>

#define B_   64
#define T_   256
#define DIN_ 512
#define H_   512
#define D_   1024
#define O_   1536
#define TB_  (T_*B_)
#define EPSf 1e-5f
#define NWG  96          // col-WGs per domain; WG w owns y-cols [16w,16w+16)
#define NSLOT (T_ + 6)   // wavefront slots: t = s - 2l

typedef short  bf16x8 __attribute__((ext_vector_type(8)));
typedef float  f32x4  __attribute__((ext_vector_type(4)));
typedef ushort u16x4  __attribute__((ext_vector_type(4)));
typedef unsigned long long ull;

#define SPLIT1(f, Hm, Lm) { __hip_bfloat16 _h = __float2bfloat16(f); (Hm) = *(ushort*)&_h; \
    __hip_bfloat16 _l = __float2bfloat16((f) - __bfloat162float(_h)); (Lm) = *(ushort*)&_l; }

__device__ inline void st_f32_coh(float* p, float v) {
    __hip_atomic_store(p, v, __ATOMIC_RELAXED, __HIP_MEMORY_SCOPE_AGENT);
}
__device__ inline void st_u16_coh(ushort* p, ushort v) {
    __hip_atomic_store(p, v, __ATOMIC_RELAXED, __HIP_MEMORY_SCOPE_AGENT);
}
__device__ inline void st_u32_coh(unsigned* p, unsigned v) {
    __hip_atomic_store(p, v, __ATOMIC_RELAXED, __HIP_MEMORY_SCOPE_AGENT);
}
__device__ inline void st_f32x2_coh(float* p, float a, float b) {
    union { float f[2]; ull u; } pk;
    pk.f[0] = a; pk.f[1] = b;
    __hip_atomic_store((ull*)p, pk.u, __ATOMIC_RELAXED, __HIP_MEMORY_SCOPE_AGENT);
}

// ---------------- mask codes: mcode[t*B+b] = mt | (mn<<1) ----------------
__global__ __launch_bounds__(256) void k_mask(const int* __restrict__ mask,
                                              int* __restrict__ mcode) {
    int g = blockIdx.x * 256 + threadIdx.x;
    int t = g >> 6, b = g & 63;
    int mt = mask[b * T_ + t] != 0;
    int mn = (t + 1 < T_) ? (mask[b * T_ + t + 1] != 0) : 0;
    mcode[g] = mt | (mn << 1);
}

// ---- x to bf16: Xb[t*64+b][k] = bf16(k<512 ? x[b][t][k] : 0) ----
__global__ __launch_bounds__(256) void k_prepx(const float* __restrict__ x,
                                               ushort* __restrict__ Xh) {
    int g  = blockIdx.x * 256 + threadIdx.x;
    int i4 = g * 4;
    int row = i4 >> 10;
    int k   = i4 & 1023;
    int t = row >> 6, b = row & 63;
    float4 v = make_float4(0.f, 0.f, 0.f, 0.f);
    if (k < 512) v = *(const float4*)&x[((size_t)b * T_ + t) * 512 + k];
    u16x4 h;
    __hip_bfloat16 b0 = __float2bfloat16(v.x); h[0] = *(ushort*)&b0;
    __hip_bfloat16 b1 = __float2bfloat16(v.y); h[1] = *(ushort*)&b1;
    __hip_bfloat16 b2 = __float2bfloat16(v.z); h[2] = *(ushort*)&b2;
    __hip_bfloat16 b3 = __float2bfloat16(v.w); h[3] = *(ushort*)&b3;
    *(u16x4*)&Xh[i4] = h;
}

// ---- transpose + split-bf16: Mt_hi[o][k]+Mt_lo[o][k] ≈ M[k][o]  (M is [D_][O_]) ----
__global__ __launch_bounds__(256) void k_prep(const float* __restrict__ M,
                                              ushort* __restrict__ Mt_hi,
                                              ushort* __restrict__ Mt_lo) {
    __shared__ float ls[64][65];
    int k0 = blockIdx.y * 64;
    int o0 = blockIdx.x * 64;
    int tid = threadIdx.x;
    int r = tid >> 2, cq = tid & 3;
#pragma unroll
    for (int j = 0; j < 4; ++j) {
        float4 v = *(const float4*)&M[(size_t)(k0 + r) * O_ + o0 + cq * 16 + j * 4];
        ls[r][cq * 16 + j * 4 + 0] = v.x;
        ls[r][cq * 16 + j * 4 + 1] = v.y;
        ls[r][cq * 16 + j * 4 + 2] = v.z;
        ls[r][cq * 16 + j * 4 + 3] = v.w;
    }
    __syncthreads();
    int ol = tid >> 2, kq = tid & 3;
    ushort th[16], tl[16];
#pragma unroll
    for (int j = 0; j < 16; ++j) {
        float v = ls[kq * 16 + j][ol];
        SPLIT1(v, th[j], tl[j]);
    }
    size_t base = (size_t)(o0 + ol) * D_ + k0 + kq * 16;
    *(int4*)&Mt_hi[base]     = *(int4*)&th[0];
    *(int4*)&Mt_hi[base + 8] = *(int4*)&th[8];
    *(int4*)&Mt_lo[base]     = *(int4*)&tl[0];
    *(int4*)&Mt_lo[base + 8] = *(int4*)&tl[8];
}

// ------ barrier: sc1-store protocol (verified round 8); per-domain flags ------
__device__ inline void gbar(unsigned* __restrict__ fl, int w, unsigned bar) {
    __syncthreads();
    asm volatile("s_waitcnt vmcnt(0)" ::: "memory");
    if (threadIdx.x == 0)
        __hip_atomic_store(&fl[w], bar, __ATOMIC_RELAXED, __HIP_MEMORY_SCOPE_AGENT);
    if (threadIdx.x < NWG) {
        while (__hip_atomic_load(&fl[threadIdx.x], __ATOMIC_RELAXED,
                                 __HIP_MEMORY_SCOPE_AGENT) < bar)
            __builtin_amdgcn_s_sleep(2);
    }
    __syncthreads();
    __builtin_amdgcn_fence(__ATOMIC_ACQUIRE, "agent");
}

// ============ 4-layer wavefront pipeline, 2 batch domains (XCD-parity) ============
// 192 WGs: dom = bx&1 (parity -> disjoint XCD sets), w = bx>>1 owns cols [16w,+16).
// waves: rt = wv&1 (16-row tile), kh = wv>>1 (K-half); deferred LDS combine.
// slot: A(all layers, 1 sync) | bar | B(reduce+tag) ~~tag~~ C(gate) | bar.
__global__ __launch_bounds__(256, 1) void k_pipe(
        const float* __restrict__ x,
        const ushort* __restrict__ Xbh,
        ushort* __restrict__ Xrh,
        ushort* __restrict__ Hbh,
        float* __restrict__ Y1, float* __restrict__ Y2,
        float* __restrict__ pstats, float* __restrict__ finals,
        unsigned* __restrict__ ftag, unsigned* __restrict__ flags,
        const ushort* __restrict__ Uth, const ushort* __restrict__ Utl,
        const ushort* __restrict__ Wth, const ushort* __restrict__ Wtl,
        const float* __restrict__ gam, const float* __restrict__ bet,
        const float* __restrict__ bias,
        const int* __restrict__ mcode, float* __restrict__ out) {
    __shared__ __hip_bfloat16 lds[4 * 16 * 1024];   // [U_hi|U_lo|W_hi|W_lo] 32KB each
    __shared__ f32x4 ldsc[4][2][64][2];             // per-layer K-half partials (16KB)
    const int bx = blockIdx.x;
    const int dom = bx & 1;            // parity -> even/odd XCDs (L2 locality)
    const int w   = bx >> 1;
    const int tid = threadIdx.x;
    const int lane = tid & 63;
    const int wv = tid >> 6;
    const int rt = wv & 1;             // row tile within domain
    const int kh = wv >> 1;            // K half
    const int lr = lane & 15;
    const int lg = lane >> 4;
    const int c0 = w * 16;
    const int br0 = dom * 32 + rt * 16;     // global row base of this wave's tile
    unsigned* fl = flags + dom * 128;
    float* pst   = pstats + (size_t)dom * 4 * 32 * NWG * 4;
    float* fin   = finals + (size_t)dom * 128 * 4;
    unsigned* ft = ftag + (size_t)dom * 128;

    // stage U/W tiles (cols c0..c0+16) into LDS, XOR-swizzled
    {
        int cl = tid >> 4, kc = tid & 15;
        const ushort* srcs0 = Uth + (size_t)(c0 + cl) * D_ + kc * 64;
        const ushort* srcs1 = Utl + (size_t)(c0 + cl) * D_ + kc * 64;
        const ushort* srcs2 = Wth + (size_t)(c0 + cl) * D_ + kc * 64;
        const ushort* srcs3 = Wtl + (size_t)(c0 + cl) * D_ + kc * 64;
        char* base = (char*)lds;
#pragma unroll
        for (int j = 0; j < 8; ++j) {
            int k = kc * 64 + j * 8;
            int off = (cl * 2048 + k * 2) ^ ((cl & 7) << 4);
            *(int4*)(base + off)           = *(const int4*)(srcs0 + j * 8);
            *(int4*)(base + 32768 + off)   = *(const int4*)(srcs1 + j * 8);
            *(int4*)(base + 65536 + off)   = *(const int4*)(srcs2 + j * 8);
            *(int4*)(base + 98304 + off)   = *(const int4*)(srcs3 + j * 8);
        }
    }
    __syncthreads();

    const int d = c0 + lr;
    const bool gate_w = (w < 64);
    const bool tanh_w = (w >= 32 && w < 64);
    float g0d = 0.f, g1d = 0.f, cd = 0.f, g0e = 0.f, g1e = 0.f, ce = 0.f;
    if (gate_w) {
        g0d = gam[d]; g1d = gam[O_ + d];
        cd  = bet[d] + bet[O_ + d] + bias[d];
    }
    if (tanh_w) {
        int e = d + 512;
        g0e = gam[e]; g1e = gam[O_ + e];
        ce  = bet[e] + bet[O_ + e] + bias[e];
    }

    // gate-wave register state (waves wv<2; wave wv owns rows dom*32+wv*16..+16)
    float h1r[4][4] = {}, fk1r[4][4] = {};
    float oh_d1[4][4] = {}, oh_d2[4][4] = {}, fkp_d1[4][4] = {};
    f32x4 acc1[4], acc2[4];

    unsigned bar = 0;
    for (int s = 0; s < NSLOT; ++s) {
        // ------- phase A: all-layer matvecs (K-split, deferred combine) -------
        f32x4 p1[4], p2[4];
#pragma unroll
        for (int l = 0; l < 4; ++l) {
            int t = s - 2 * l;
            bool act = (t >= 0) && (t < T_);
            p1[l] = (f32x4){0,0,0,0};
            p2[l] = (f32x4){0,0,0,0};
            if (act) {
                const ushort* xsh;
                if (l == 0) {
                    xsh = Xbh + ((size_t)t * B_ + br0 + lr) * D_ + kh * 512;
                } else {
                    xsh = Xrh + (((size_t)l * 3 + (t % 3)) * B_ + br0 + lr) * D_ + kh * 512;
                }
                const ushort* hsh = Hbh + ((size_t)l * B_ + br0 + lr) * D_ + kh * 512;
                const char* lb = (const char*)lds;
                f32x4 a10 = {0,0,0,0}, a11 = {0,0,0,0};
                f32x4 a20 = {0,0,0,0}, a21 = {0,0,0,0};
#pragma unroll 4
                for (int kc = 0; kc < 16; ++kc) {
                    int kloc = kc * 32 + lg * 8;
                    int kglob = kh * 512 + kloc;
                    int off = (lr * 2048 + kglob * 2) ^ ((lr & 7) << 4);
                    bf16x8 xa = *(const bf16x8*)(xsh + kloc);
                    bf16x8 ha = *(const bf16x8*)(hsh + kloc);
                    bf16x8 ubh = *(const bf16x8*)(lb + off);
                    bf16x8 ubl = *(const bf16x8*)(lb + 32768 + off);
                    bf16x8 wbh = *(const bf16x8*)(lb + 65536 + off);
                    bf16x8 wbl = *(const bf16x8*)(lb + 98304 + off);
                    a10 = __builtin_amdgcn_mfma_f32_16x16x32_bf16(xa, wbh, a10, 0, 0, 0);
                    a11 = __builtin_amdgcn_mfma_f32_16x16x32_bf16(xa, wbl, a11, 0, 0, 0);
                    a20 = __builtin_amdgcn_mfma_f32_16x16x32_bf16(ha, ubh, a20, 0, 0, 0);
                    a21 = __builtin_amdgcn_mfma_f32_16x16x32_bf16(ha, ubl, a21, 0, 0, 0);
                }
                p1[l] = a10 + a11;
                p2[l] = a20 + a21;
                if (kh == 1) {
                    ldsc[l][rt][lane][0] = p1[l];
                    ldsc[l][rt][lane][1] = p2[l];
                }
            }
        }
        __syncthreads();
        if (kh == 0) {
#pragma unroll
            for (int l = 0; l < 4; ++l) {
                int t = s - 2 * l;
                bool act = (t >= 0) && (t < T_);
                if (!act) continue;
                acc1[l] = p1[l] + ldsc[l][rt][lane][0];
                acc2[l] = p2[l] + ldsc[l][rt][lane][1];
                // per-row partial stats -> pstats[(l,lrow,w)] (no contention)
#pragma unroll
                for (int j = 0; j < 4; ++j) {
                    float s1 = acc1[l][j], q1 = s1 * s1;
                    float s2 = acc2[l][j], q2 = s2 * s2;
#pragma unroll
                    for (int m = 1; m < 16; m <<= 1) {
                        s1 += __shfl_xor(s1, m); q1 += __shfl_xor(q1, m);
                        s2 += __shfl_xor(s2, m); q2 += __shfl_xor(q2, m);
                    }
                    if (lr == 0) {
                        int lrow = rt * 16 + lg * 4 + j;
                        float* sp = &pst[(((size_t)l * 32 + lrow) * NWG + w) * 4];
                        st_f32x2_coh(sp, s1, q1);
                        st_f32x2_coh(sp + 2, s2, q2);
                    }
                }
                // export tanh-partner cols (w>=64)
                if (w >= 64) {
                    int cexp = c0 + lr - 1024;
#pragma unroll
                    for (int j = 0; j < 4; ++j) {
                        int b = br0 + lg * 4 + j;
                        st_f32_coh(&Y1[((size_t)l * B_ + b) * 512 + cexp], acc1[l][j]);
                        st_f32_coh(&Y2[((size_t)l * B_ + b) * 512 + cexp], acc2[l][j]);
                    }
                }
            }
        }
        gbar(fl, w, ++bar);

        // ------- phase B: stats reduce (pair = w + 96*wv, wv<2) + tag -------
        if (wv < 2) {
            int pair = w + NWG * wv;
            if (pair < 128) {
                const float* pp = &pst[(size_t)pair * NWG * 4];
                float s1 = 0.f, q1 = 0.f, s2 = 0.f, q2 = 0.f;
                if (lane < 32) {
#pragma unroll
                    for (int i = 0; i < 3; ++i) {
                        float4 v = *(const float4*)(pp + (lane + i * 32) * 4);
                        s1 += v.x; q1 += v.y; s2 += v.z; q2 += v.w;
                    }
                }
#pragma unroll
                for (int m = 1; m < 32; m <<= 1) {
                    s1 += __shfl_xor(s1, m); q1 += __shfl_xor(q1, m);
                    s2 += __shfl_xor(s2, m); q2 += __shfl_xor(q2, m);
                }
                if (lane == 0) {
                    float m1 = s1 * (1.f / O_);
                    float v1 = q1 * (1.f / O_) - m1 * m1;
                    float i1 = 1.f / (sqrtf(v1 + EPSf) + EPSf);
                    float m2 = s2 * (1.f / O_);
                    float v2 = q2 * (1.f / O_) - m2 * m2;
                    float i2 = 1.f / (sqrtf(v2 + EPSf) + EPSf);
                    st_f32x2_coh(&fin[(size_t)pair * 4], m1, i1);
                    st_f32x2_coh(&fin[(size_t)pair * 4 + 2], m2, i2);
                    asm volatile("s_waitcnt vmcnt(0)" ::: "memory");
                    st_u32_coh(&ft[pair], (unsigned)(s + 1));
                }
            }
        }

        // ------- phase C: gating (waves wv<2; tag-synced finals) -------
        if (gate_w && wv < 2) {
#pragma unroll
            for (int li = 0; li < 4; ++li) {
                const int l = 3 - li;
                const int lp = (l > 0) ? l - 1 : 0;
                int t = s - 2 * l;
                bool act = (t >= 0) && (t < T_);
                float ohn[4], ofkn[4];
                if (act) {
                    int b_base = dom * 32 + wv * 16 + lg * 4;
                    int4 mc4 = *(const int4*)&mcode[t * B_ + b_base];
                    int mcarr[4] = {mc4.x, mc4.y, mc4.z, mc4.w};
#pragma unroll
                    for (int j = 0; j < 4; ++j) {
                        int b = b_base + j;
                        int lrow = wv * 16 + lg * 4 + j;
                        int pair = l * 32 + lrow;
                        while (__hip_atomic_load(&ft[pair], __ATOMIC_RELAXED,
                                                 __HIP_MEMORY_SCOPE_AGENT) < (unsigned)(s + 1))
                            __builtin_amdgcn_s_sleep(1);
                        union { ull u[2]; float f[4]; } fv;
                        fv.u[0] = __hip_atomic_load((ull*)&fin[(size_t)pair * 4],
                                                    __ATOMIC_RELAXED, __HIP_MEMORY_SCOPE_AGENT);
                        fv.u[1] = __hip_atomic_load((ull*)&fin[(size_t)pair * 4 + 2],
                                                    __ATOMIC_RELAXED, __HIP_MEMORY_SCOPE_AGENT);
                        float m1 = fv.f[0], i1 = fv.f[1], m2 = fv.f[2], i2 = fv.f[3];
                        float y1 = acc1[l][j], y2 = acc2[l][j];
                        float td = g0d * (y1 - m1) * i1 + g1d * (y2 - m2) * i2 + cd;
                        float fkc = fminf(fmaxf(0.2f * td + 0.5f, 0.f), 1.f);
                        float hpad = 0.f;
                        if (tanh_w) {
                            float y1e = Y1[((size_t)l * B_ + b) * 512 + (d - 512)];
                            float y2e = Y2[((size_t)l * B_ + b) * 512 + (d - 512)];
                            float te = g0e * (y1e - m1) * i1 + g1e * (y2e - m2) * i2 + ce;
                            hpad = tanhf(te);
                        }
                        float xt;
                        if (l == 0)
                            xt = (d < 512) ? x[((size_t)b * T_ + t) * 512 + d] : 0.f;
                        else
                            xt = oh_d2[lp][j];
                        float fkp = (l > 0 && t + 1 < T_) ? fkp_d1[lp][j] : 0.f;
                        float hc = (1.f - fkc) * xt + fkc * hpad;
                        float h  = fkp * h1r[l][j] + (1.f - fkp) * hc;
                        float fk = fkp + (1.f - fkp) * fkc;
                        int mt = mcarr[j] & 1, mn = (mcarr[j] >> 1) & 1;
                        if (mt && !mn) fk = 0.f;
                        float oh  = mt ? h  : h1r[l][j];
                        float ofk = mt ? fk : fk1r[l][j];
                        h1r[l][j] = oh; fk1r[l][j] = ofk;
                        __hip_bfloat16 hb = __float2bfloat16(oh);
                        ushort hi = *(ushort*)&hb;
                        st_u16_coh(Hbh + ((size_t)l * B_ + b) * D_ + d, hi);
                        if (l < 3) {
                            size_t xb = (((size_t)(l + 1) * 3 + (t % 3)) * B_ + b) * D_ + d;
                            st_u16_coh(Xrh + xb, hi);
                        }
                        if (l == 3 && t == T_ - 1 && d >= 512)
                            out[(size_t)b * 512 + (d - 512)] = oh;
                        ohn[j] = oh; ofkn[j] = ofk;
                    }
                }
#pragma unroll
                for (int j = 0; j < 4; ++j) {
                    oh_d2[l][j] = oh_d1[l][j];
                    if (act) { oh_d1[l][j] = ohn[j]; fkp_d1[l][j] = ofkn[j]; }
                }
            }
        }
        gbar(fl, w, ++bar);
    }
}

extern "C" void kernel_launch(void* const* d_in, const int* in_sizes, int n_in,
                              void* d_out, int out_size, void* d_ws, size_t ws_size,
                              hipStream_t stream) {
    (void)in_sizes; (void)n_in; (void)out_size;
    const float* x      = (const float*)d_in[0];
    const int*   mask   = (const int*)d_in[1];
    const float* W      = (const float*)d_in[2];
    const float* U      = (const float*)d_in[3];
    const float* bias   = (const float*)d_in[4];
    const float* gammas = (const float*)d_in[5];
    const float* betas  = (const float*)d_in[6];

    float* ws = (float*)d_ws;
    float* Y1    = ws;                                     // 4*B_*512
    float* Y2    = Y1 + (size_t)4 * B_ * 512;              // 4*B_*512
    float* pstats = Y2 + (size_t)4 * B_ * 512;             // 2*4*32*96*4
    float* finals = pstats + (size_t)2 * 4 * 32 * NWG * 4; // 2*128*4
    unsigned* ftag  = (unsigned*)(finals + 2 * 128 * 4);   // 2*128
    unsigned* flags = ftag + 2 * 128;                      // 256
    int* mcode = (int*)(flags + 256);                      // TB_
    ushort* Xbh = (ushort*)(mcode + TB_);                  // TB_*D_
    ushort* Xrh = Xbh + (size_t)TB_ * D_;                  // 4*3*B_*D_
    ushort* Hbh = Xrh + (size_t)4 * 3 * B_ * D_;           // 4*B_*D_
    ushort* Uth = Hbh + (size_t)4 * B_ * D_;               // O_*D_
    ushort* Utl = Uth + (size_t)O_ * D_;
    ushort* Wth = Utl + (size_t)O_ * D_;
    ushort* Wtl = Wth + (size_t)O_ * D_;
    size_t need_bytes = ((char*)(Wtl + (size_t)O_ * D_)) - ((char*)d_ws);
    if (ws_size < need_bytes) return;

    k_prepx<<<TB_ * D_ / 4 / 256, 256, 0, stream>>>(x, Xbh);
    k_mask<<<TB_ / 256, 256, 0, stream>>>(mask, mcode);
    k_prep<<<dim3(O_ / 64, D_ / 64), 256, 0, stream>>>(U, Uth, Utl);
    k_prep<<<dim3(O_ / 64, D_ / 64), 256, 0, stream>>>(W, Wth, Wtl);
    (void)hipMemsetAsync(Hbh, 0, sizeof(ushort) * (size_t)4 * B_ * D_, stream);
    (void)hipMemsetAsync(pstats, 0, sizeof(float) * (size_t)2 * 4 * 32 * NWG * 4, stream);
    (void)hipMemsetAsync(ftag, 0, sizeof(unsigned) * 2 * 128, stream);
    (void)hipMemsetAsync(flags, 0, sizeof(unsigned) * 256, stream);

    k_pipe<<<2 * NWG, 256, 0, stream>>>(x, Xbh, Xrh, Hbh,
                                        Y1, Y2, pstats, finals, ftag, flags,
                                        Uth, Utl, Wth, Wtl,
                                        gammas, betas, bias, mcode, (float*)d_out);
}

// Round 17
// 12759.846 us; speedup vs baseline: 2.1059x; 1.1877x over previous
//
#include <hip/hip_runtime.h>
#include <hip/hip_bf16.h>
#include <math.h>

#define B_   64
#define T_   256
#define DIN_ 512
#define H_   512
#define D_   1024
#define O_   1536
#define TB_  (T_*B_)
#define EPSf 1e-5f
#define NWG  96          // col-WGs per domain; WG w owns y-cols [16w,16w+16)
#define NSLOT (T_ + 6)   // wavefront slots: t = s - 2l

typedef short  bf16x8 __attribute__((ext_vector_type(8)));
typedef float  f32x4  __attribute__((ext_vector_type(4)));
typedef ushort u16x4  __attribute__((ext_vector_type(4)));
typedef unsigned long long ull;

#define SPLIT1(f, Hm, Lm) { __hip_bfloat16 _h = __float2bfloat16(f); (Hm) = *(ushort*)&_h; \
    __hip_bfloat16 _l = __float2bfloat16((f) - __bfloat162float(_h)); (Lm) = *(ushort*)&_l; }

__device__ inline void st_f32_coh(float* p, float v) {
    __hip_atomic_store(p, v, __ATOMIC_RELAXED, __HIP_MEMORY_SCOPE_AGENT);
}
__device__ inline void st_u16_coh(ushort* p, ushort v) {
    __hip_atomic_store(p, v, __ATOMIC_RELAXED, __HIP_MEMORY_SCOPE_AGENT);
}
__device__ inline void st_u32_coh(unsigned* p, unsigned v) {
    __hip_atomic_store(p, v, __ATOMIC_RELAXED, __HIP_MEMORY_SCOPE_AGENT);
}
__device__ inline void st_f32x2_coh(float* p, float a, float b) {
    union { float f[2]; ull u; } pk;
    pk.f[0] = a; pk.f[1] = b;
    __hip_atomic_store((ull*)p, pk.u, __ATOMIC_RELAXED, __HIP_MEMORY_SCOPE_AGENT);
}

// ---------------- mask codes: mcode[t*B+b] = mt | (mn<<1) ----------------
__global__ __launch_bounds__(256) void k_mask(const int* __restrict__ mask,
                                              int* __restrict__ mcode) {
    int g = blockIdx.x * 256 + threadIdx.x;
    int t = g >> 6, b = g & 63;
    int mt = mask[b * T_ + t] != 0;
    int mn = (t + 1 < T_) ? (mask[b * T_ + t + 1] != 0) : 0;
    mcode[g] = mt | (mn << 1);
}

// ---- x to bf16: Xb[t*64+b][k] = bf16(k<512 ? x[b][t][k] : 0) ----
__global__ __launch_bounds__(256) void k_prepx(const float* __restrict__ x,
                                               ushort* __restrict__ Xh) {
    int g  = blockIdx.x * 256 + threadIdx.x;
    int i4 = g * 4;
    int row = i4 >> 10;
    int k   = i4 & 1023;
    int t = row >> 6, b = row & 63;
    float4 v = make_float4(0.f, 0.f, 0.f, 0.f);
    if (k < 512) v = *(const float4*)&x[((size_t)b * T_ + t) * 512 + k];
    u16x4 h;
    __hip_bfloat16 b0 = __float2bfloat16(v.x); h[0] = *(ushort*)&b0;
    __hip_bfloat16 b1 = __float2bfloat16(v.y); h[1] = *(ushort*)&b1;
    __hip_bfloat16 b2 = __float2bfloat16(v.z); h[2] = *(ushort*)&b2;
    __hip_bfloat16 b3 = __float2bfloat16(v.w); h[3] = *(ushort*)&b3;
    *(u16x4*)&Xh[i4] = h;
}

// ---- transpose + split-bf16: Mt_hi[o][k]+Mt_lo[o][k] ≈ M[k][o]  (M is [D_][O_]) ----
__global__ __launch_bounds__(256) void k_prep(const float* __restrict__ M,
                                              ushort* __restrict__ Mt_hi,
                                              ushort* __restrict__ Mt_lo) {
    __shared__ float ls[64][65];
    int k0 = blockIdx.y * 64;
    int o0 = blockIdx.x * 64;
    int tid = threadIdx.x;
    int r = tid >> 2, cq = tid & 3;
#pragma unroll
    for (int j = 0; j < 4; ++j) {
        float4 v = *(const float4*)&M[(size_t)(k0 + r) * O_ + o0 + cq * 16 + j * 4];
        ls[r][cq * 16 + j * 4 + 0] = v.x;
        ls[r][cq * 16 + j * 4 + 1] = v.y;
        ls[r][cq * 16 + j * 4 + 2] = v.z;
        ls[r][cq * 16 + j * 4 + 3] = v.w;
    }
    __syncthreads();
    int ol = tid >> 2, kq = tid & 3;
    ushort th[16], tl[16];
#pragma unroll
    for (int j = 0; j < 16; ++j) {
        float v = ls[kq * 16 + j][ol];
        SPLIT1(v, th[j], tl[j]);
    }
    size_t base = (size_t)(o0 + ol) * D_ + k0 + kq * 16;
    *(int4*)&Mt_hi[base]     = *(int4*)&th[0];
    *(int4*)&Mt_hi[base + 8] = *(int4*)&th[8];
    *(int4*)&Mt_lo[base]     = *(int4*)&tl[0];
    *(int4*)&Mt_lo[base + 8] = *(int4*)&tl[8];
}

// ------ barrier: sc1-store protocol (verified round 8); per-domain flags ------
__device__ inline void gbar(unsigned* __restrict__ fl, int w, unsigned bar) {
    __syncthreads();
    asm volatile("s_waitcnt vmcnt(0)" ::: "memory");
    if (threadIdx.x == 0)
        __hip_atomic_store(&fl[w], bar, __ATOMIC_RELAXED, __HIP_MEMORY_SCOPE_AGENT);
    if (threadIdx.x < NWG) {
        while (__hip_atomic_load(&fl[threadIdx.x], __ATOMIC_RELAXED,
                                 __HIP_MEMORY_SCOPE_AGENT) < bar)
            __builtin_amdgcn_s_sleep(2);
    }
    __syncthreads();
    __builtin_amdgcn_fence(__ATOMIC_ACQUIRE, "agent");
}

// ============ 4-layer wavefront pipeline, 2 batch domains (XCD-parity) ============
// 192 WGs: dom = bx&1 (parity -> disjoint XCD sets), w = bx>>1 owns cols [16w,+16).
// waves: rt = wv&1 (16-row tile), kh = wv>>1 (K-half); deferred LDS combine.
// slot: A(all layers, 1 sync) | bar | B(reduce+tag) ~~tag-all~~ C(gate) | bar.
__global__ __launch_bounds__(256, 1) void k_pipe(
        const float* __restrict__ x,
        const ushort* __restrict__ Xbh,
        ushort* __restrict__ Xrh,
        ushort* __restrict__ Hbh,
        float* __restrict__ Y1, float* __restrict__ Y2,
        float* __restrict__ pstats, float* __restrict__ finals,
        unsigned* __restrict__ ftag, unsigned* __restrict__ flags,
        const ushort* __restrict__ Uth, const ushort* __restrict__ Utl,
        const ushort* __restrict__ Wth, const ushort* __restrict__ Wtl,
        const float* __restrict__ gam, const float* __restrict__ bet,
        const float* __restrict__ bias,
        const int* __restrict__ mcode, float* __restrict__ out) {
    __shared__ __hip_bfloat16 lds[4 * 16 * 1024];   // [U_hi|U_lo|W_hi|W_lo] 32KB each
    __shared__ f32x4 ldsc[4][2][64][2];             // per-layer K-half partials (16KB)
    const int bx = blockIdx.x;
    const int dom = bx & 1;            // parity -> even/odd XCDs (L2 locality)
    const int w   = bx >> 1;
    const int tid = threadIdx.x;
    const int lane = tid & 63;
    const int wv = tid >> 6;
    const int rt = wv & 1;             // row tile within domain
    const int kh = wv >> 1;            // K half
    const int lr = lane & 15;
    const int lg = lane >> 4;
    const int c0 = w * 16;
    const int br0 = dom * 32 + rt * 16;     // global row base of this wave's tile
    unsigned* fl = flags + dom * 128;
    float* pst   = pstats + (size_t)dom * 4 * 32 * NWG * 4;
    float* fin   = finals + (size_t)dom * 128 * 4;
    unsigned* ft = ftag + (size_t)dom * 128;

    // stage U/W tiles (cols c0..c0+16) into LDS, XOR-swizzled
    {
        int cl = tid >> 4, kc = tid & 15;
        const ushort* srcs0 = Uth + (size_t)(c0 + cl) * D_ + kc * 64;
        const ushort* srcs1 = Utl + (size_t)(c0 + cl) * D_ + kc * 64;
        const ushort* srcs2 = Wth + (size_t)(c0 + cl) * D_ + kc * 64;
        const ushort* srcs3 = Wtl + (size_t)(c0 + cl) * D_ + kc * 64;
        char* base = (char*)lds;
#pragma unroll
        for (int j = 0; j < 8; ++j) {
            int k = kc * 64 + j * 8;
            int off = (cl * 2048 + k * 2) ^ ((cl & 7) << 4);
            *(int4*)(base + off)           = *(const int4*)(srcs0 + j * 8);
            *(int4*)(base + 32768 + off)   = *(const int4*)(srcs1 + j * 8);
            *(int4*)(base + 65536 + off)   = *(const int4*)(srcs2 + j * 8);
            *(int4*)(base + 98304 + off)   = *(const int4*)(srcs3 + j * 8);
        }
    }
    __syncthreads();

    const int d = c0 + lr;
    const bool gate_w = (w < 64);
    const bool tanh_w = (w >= 32 && w < 64);
    float g0d = 0.f, g1d = 0.f, cd = 0.f, g0e = 0.f, g1e = 0.f, ce = 0.f;
    if (gate_w) {
        g0d = gam[d]; g1d = gam[O_ + d];
        cd  = bet[d] + bet[O_ + d] + bias[d];
    }
    if (tanh_w) {
        int e = d + 512;
        g0e = gam[e]; g1e = gam[O_ + e];
        ce  = bet[e] + bet[O_ + e] + bias[e];
    }

    // gate-wave register state (waves wv<2; wave wv owns rows dom*32+wv*16..+16)
    float h1r[4][4] = {}, fk1r[4][4] = {};
    float oh_d1[4][4] = {}, oh_d2[4][4] = {}, fkp_d1[4][4] = {};
    f32x4 acc1[4], acc2[4];

    unsigned bar = 0;
    for (int s = 0; s < NSLOT; ++s) {
        // ------- phase A: all-layer matvecs (K-split, deferred combine) -------
        f32x4 p1[4], p2[4];
#pragma unroll
        for (int l = 0; l < 4; ++l) {
            int t = s - 2 * l;
            bool act = (t >= 0) && (t < T_);
            p1[l] = (f32x4){0,0,0,0};
            p2[l] = (f32x4){0,0,0,0};
            if (act) {
                const ushort* xsh;
                if (l == 0) {
                    xsh = Xbh + ((size_t)t * B_ + br0 + lr) * D_ + kh * 512;
                } else {
                    xsh = Xrh + (((size_t)l * 3 + (t % 3)) * B_ + br0 + lr) * D_ + kh * 512;
                }
                const ushort* hsh = Hbh + ((size_t)l * B_ + br0 + lr) * D_ + kh * 512;
                const char* lb = (const char*)lds;
                f32x4 a10 = {0,0,0,0}, a11 = {0,0,0,0};
                f32x4 a20 = {0,0,0,0}, a21 = {0,0,0,0};
#pragma unroll 4
                for (int kc = 0; kc < 16; ++kc) {
                    int kloc = kc * 32 + lg * 8;
                    int kglob = kh * 512 + kloc;
                    int off = (lr * 2048 + kglob * 2) ^ ((lr & 7) << 4);
                    bf16x8 xa = *(const bf16x8*)(xsh + kloc);
                    bf16x8 ha = *(const bf16x8*)(hsh + kloc);
                    bf16x8 ubh = *(const bf16x8*)(lb + off);
                    bf16x8 ubl = *(const bf16x8*)(lb + 32768 + off);
                    bf16x8 wbh = *(const bf16x8*)(lb + 65536 + off);
                    bf16x8 wbl = *(const bf16x8*)(lb + 98304 + off);
                    a10 = __builtin_amdgcn_mfma_f32_16x16x32_bf16(xa, wbh, a10, 0, 0, 0);
                    a11 = __builtin_amdgcn_mfma_f32_16x16x32_bf16(xa, wbl, a11, 0, 0, 0);
                    a20 = __builtin_amdgcn_mfma_f32_16x16x32_bf16(ha, ubh, a20, 0, 0, 0);
                    a21 = __builtin_amdgcn_mfma_f32_16x16x32_bf16(ha, ubl, a21, 0, 0, 0);
                }
                p1[l] = a10 + a11;
                p2[l] = a20 + a21;
                if (kh == 1) {
                    ldsc[l][rt][lane][0] = p1[l];
                    ldsc[l][rt][lane][1] = p2[l];
                }
            }
        }
        __syncthreads();
        if (kh == 0) {
#pragma unroll
            for (int l = 0; l < 4; ++l) {
                int t = s - 2 * l;
                bool act = (t >= 0) && (t < T_);
                if (!act) continue;
                acc1[l] = p1[l] + ldsc[l][rt][lane][0];
                acc2[l] = p2[l] + ldsc[l][rt][lane][1];
                // per-row partial stats -> pstats[(l,lrow,w)] (no contention)
#pragma unroll
                for (int j = 0; j < 4; ++j) {
                    float s1 = acc1[l][j], q1 = s1 * s1;
                    float s2 = acc2[l][j], q2 = s2 * s2;
#pragma unroll
                    for (int m = 1; m < 16; m <<= 1) {
                        s1 += __shfl_xor(s1, m); q1 += __shfl_xor(q1, m);
                        s2 += __shfl_xor(s2, m); q2 += __shfl_xor(q2, m);
                    }
                    if (lr == 0) {
                        int lrow = rt * 16 + lg * 4 + j;
                        float* sp = &pst[(((size_t)l * 32 + lrow) * NWG + w) * 4];
                        st_f32x2_coh(sp, s1, q1);
                        st_f32x2_coh(sp + 2, s2, q2);
                    }
                }
                // export tanh-partner cols (w>=64)
                if (w >= 64) {
                    int cexp = c0 + lr - 1024;
#pragma unroll
                    for (int j = 0; j < 4; ++j) {
                        int b = br0 + lg * 4 + j;
                        st_f32_coh(&Y1[((size_t)l * B_ + b) * 512 + cexp], acc1[l][j]);
                        st_f32_coh(&Y2[((size_t)l * B_ + b) * 512 + cexp], acc2[l][j]);
                    }
                }
            }
        }
        gbar(fl, w, ++bar);

        // ------- phase B: stats reduce (pair = w + 96*wv, wv<2) + tag -------
        if (wv < 2) {
            int pair = w + NWG * wv;
            if (pair < 128) {
                const float* pp = &pst[(size_t)pair * NWG * 4];
                float s1 = 0.f, q1 = 0.f, s2 = 0.f, q2 = 0.f;
                if (lane < 32) {
#pragma unroll
                    for (int i = 0; i < 3; ++i) {
                        float4 v = *(const float4*)(pp + (lane + i * 32) * 4);
                        s1 += v.x; q1 += v.y; s2 += v.z; q2 += v.w;
                    }
                }
#pragma unroll
                for (int m = 1; m < 32; m <<= 1) {
                    s1 += __shfl_xor(s1, m); q1 += __shfl_xor(q1, m);
                    s2 += __shfl_xor(s2, m); q2 += __shfl_xor(q2, m);
                }
                if (lane == 0) {
                    float m1 = s1 * (1.f / O_);
                    float v1 = q1 * (1.f / O_) - m1 * m1;
                    float i1 = 1.f / (sqrtf(v1 + EPSf) + EPSf);
                    float m2 = s2 * (1.f / O_);
                    float v2 = q2 * (1.f / O_) - m2 * m2;
                    float i2 = 1.f / (sqrtf(v2 + EPSf) + EPSf);
                    st_f32x2_coh(&fin[(size_t)pair * 4], m1, i1);
                    st_f32x2_coh(&fin[(size_t)pair * 4 + 2], m2, i2);
                    asm volatile("s_waitcnt vmcnt(0)" ::: "memory");
                    st_u32_coh(&ft[pair], (unsigned)(s + 1));
                }
            }
        }

        // ------- phase C: gating (waves wv<2); spin-all then burst loads -------
        if (gate_w && wv < 2) {
            const int lrow0 = wv * 16 + lg * 4;       // this thread's first local row
            // 1. spin until ALL 16 (l,row) tags ready — 16 parallel polls per pass
            for (;;) {
                bool ready = true;
#pragma unroll
                for (int l = 0; l < 4; ++l) {
                    int t = s - 2 * l;
                    if (t < 0 || t >= T_) continue;
                    unsigned t0 = __hip_atomic_load(&ft[l * 32 + lrow0 + 0], __ATOMIC_RELAXED, __HIP_MEMORY_SCOPE_AGENT);
                    unsigned t1 = __hip_atomic_load(&ft[l * 32 + lrow0 + 1], __ATOMIC_RELAXED, __HIP_MEMORY_SCOPE_AGENT);
                    unsigned t2 = __hip_atomic_load(&ft[l * 32 + lrow0 + 2], __ATOMIC_RELAXED, __HIP_MEMORY_SCOPE_AGENT);
                    unsigned t3 = __hip_atomic_load(&ft[l * 32 + lrow0 + 3], __ATOMIC_RELAXED, __HIP_MEMORY_SCOPE_AGENT);
                    unsigned mn4 = min(min(t0, t1), min(t2, t3));
                    ready = ready && (mn4 >= (unsigned)(s + 1));
                }
                if (ready) break;
                __builtin_amdgcn_s_sleep(1);
            }
            // 2. per-layer: burst-load finals (plain: L2 fresh-for-slot) + mc + y, compute
#pragma unroll
            for (int li = 0; li < 4; ++li) {
                const int l = 3 - li;
                const int lp = (l > 0) ? l - 1 : 0;
                int t = s - 2 * l;
                bool act = (t >= 0) && (t < T_);
                float ohn[4], ofkn[4];
                if (act) {
                    int b_base = dom * 32 + wv * 16 + lg * 4;
                    int4 mc4 = *(const int4*)&mcode[t * B_ + b_base];
                    int mcarr[4] = {mc4.x, mc4.y, mc4.z, mc4.w};
                    float4 sv[4];
                    float y1e[4], y2e[4];
#pragma unroll
                    for (int j = 0; j < 4; ++j)
                        sv[j] = *(const float4*)&fin[(size_t)(l * 32 + lrow0 + j) * 4];
                    if (tanh_w) {
#pragma unroll
                        for (int j = 0; j < 4; ++j) {
                            int b = b_base + j;
                            y1e[j] = Y1[((size_t)l * B_ + b) * 512 + (d - 512)];
                            y2e[j] = Y2[((size_t)l * B_ + b) * 512 + (d - 512)];
                        }
                    }
#pragma unroll
                    for (int j = 0; j < 4; ++j) {
                        int b = b_base + j;
                        float m1 = sv[j].x, i1 = sv[j].y, m2 = sv[j].z, i2 = sv[j].w;
                        float y1 = acc1[l][j], y2 = acc2[l][j];
                        float td = g0d * (y1 - m1) * i1 + g1d * (y2 - m2) * i2 + cd;
                        float fkc = fminf(fmaxf(0.2f * td + 0.5f, 0.f), 1.f);
                        float hpad = 0.f;
                        if (tanh_w) {
                            float te = g0e * (y1e[j] - m1) * i1 + g1e * (y2e[j] - m2) * i2 + ce;
                            hpad = tanhf(te);
                        }
                        float xt;
                        if (l == 0)
                            xt = (d < 512) ? x[((size_t)b * T_ + t) * 512 + d] : 0.f;
                        else
                            xt = oh_d2[lp][j];
                        float fkp = (l > 0 && t + 1 < T_) ? fkp_d1[lp][j] : 0.f;
                        float hc = (1.f - fkc) * xt + fkc * hpad;
                        float h  = fkp * h1r[l][j] + (1.f - fkp) * hc;
                        float fk = fkp + (1.f - fkp) * fkc;
                        int mt = mcarr[j] & 1, mn = (mcarr[j] >> 1) & 1;
                        if (mt && !mn) fk = 0.f;
                        float oh  = mt ? h  : h1r[l][j];
                        float ofk = mt ? fk : fk1r[l][j];
                        h1r[l][j] = oh; fk1r[l][j] = ofk;
                        __hip_bfloat16 hb = __float2bfloat16(oh);
                        ushort hi = *(ushort*)&hb;
                        st_u16_coh(Hbh + ((size_t)l * B_ + b) * D_ + d, hi);
                        if (l < 3) {
                            size_t xb = (((size_t)(l + 1) * 3 + (t % 3)) * B_ + b) * D_ + d;
                            st_u16_coh(Xrh + xb, hi);
                        }
                        if (l == 3 && t == T_ - 1 && d >= 512)
                            out[(size_t)b * 512 + (d - 512)] = oh;
                        ohn[j] = oh; ofkn[j] = ofk;
                    }
                }
#pragma unroll
                for (int j = 0; j < 4; ++j) {
                    oh_d2[l][j] = oh_d1[l][j];
                    if (act) { oh_d1[l][j] = ohn[j]; fkp_d1[l][j] = ofkn[j]; }
                }
            }
        }
        gbar(fl, w, ++bar);
    }
}

extern "C" void kernel_launch(void* const* d_in, const int* in_sizes, int n_in,
                              void* d_out, int out_size, void* d_ws, size_t ws_size,
                              hipStream_t stream) {
    (void)in_sizes; (void)n_in; (void)out_size;
    const float* x      = (const float*)d_in[0];
    const int*   mask   = (const int*)d_in[1];
    const float* W      = (const float*)d_in[2];
    const float* U      = (const float*)d_in[3];
    const float* bias   = (const float*)d_in[4];
    const float* gammas = (const float*)d_in[5];
    const float* betas  = (const float*)d_in[6];

    float* ws = (float*)d_ws;
    float* Y1    = ws;                                     // 4*B_*512
    float* Y2    = Y1 + (size_t)4 * B_ * 512;              // 4*B_*512
    float* pstats = Y2 + (size_t)4 * B_ * 512;             // 2*4*32*96*4
    float* finals = pstats + (size_t)2 * 4 * 32 * NWG * 4; // 2*128*4
    unsigned* ftag  = (unsigned*)(finals + 2 * 128 * 4);   // 2*128
    unsigned* flags = ftag + 2 * 128;                      // 256
    int* mcode = (int*)(flags + 256);                      // TB_
    ushort* Xbh = (ushort*)(mcode + TB_);                  // TB_*D_
    ushort* Xrh = Xbh + (size_t)TB_ * D_;                  // 4*3*B_*D_
    ushort* Hbh = Xrh + (size_t)4 * 3 * B_ * D_;           // 4*B_*D_
    ushort* Uth = Hbh + (size_t)4 * B_ * D_;               // O_*D_
    ushort* Utl = Uth + (size_t)O_ * D_;
    ushort* Wth = Utl + (size_t)O_ * D_;
    ushort* Wtl = Wth + (size_t)O_ * D_;
    size_t need_bytes = ((char*)(Wtl + (size_t)O_ * D_)) - ((char*)d_ws);
    if (ws_size < need_bytes) return;

    k_prepx<<<TB_ * D_ / 4 / 256, 256, 0, stream>>>(x, Xbh);
    k_mask<<<TB_ / 256, 256, 0, stream>>>(mask, mcode);
    k_prep<<<dim3(O_ / 64, D_ / 64), 256, 0, stream>>>(U, Uth, Utl);
    k_prep<<<dim3(O_ / 64, D_ / 64), 256, 0, stream>>>(W, Wth, Wtl);
    (void)hipMemsetAsync(Hbh, 0, sizeof(ushort) * (size_t)4 * B_ * D_, stream);
    (void)hipMemsetAsync(pstats, 0, sizeof(float) * (size_t)2 * 4 * 32 * NWG * 4, stream);
    (void)hipMemsetAsync(ftag, 0, sizeof(unsigned) * 2 * 128, stream);
    (void)hipMemsetAsync(flags, 0, sizeof(unsigned) * 256, stream);

    k_pipe<<<2 * NWG, 256, 0, stream>>>(x, Xbh, Xrh, Hbh,
                                        Y1, Y2, pstats, finals, ftag, flags,
                                        Uth, Utl, Wth, Wtl,
                                        gammas, betas, bias, mcode, (float*)d_out);
}